// Round 1
// baseline (561.712 us; speedup 1.0000x reference)
//
#include <hip/hip_runtime.h>
#include <hip/hip_bf16.h>
#include <stdint.h>

#define D_H 128

// ---------------- degree count ----------------
__global__ void k_count(const int* __restrict__ dst, int* __restrict__ cnt, int E) {
    int e = blockIdx.x * 256 + threadIdx.x;
    if (e < E) atomicAdd(&cnt[dst[e]], 1);
}

// dis[i] = 1/sqrt(deg_in(i) + 1)   (self-loop included; deg>=1 always)
__global__ void k_dis(const int* __restrict__ cnt, float* __restrict__ dis, int N) {
    int i = blockIdx.x * 256 + threadIdx.x;
    if (i < N) dis[i] = 1.0f / sqrtf((float)(cnt[i] + 1));
}

// ---------------- exclusive scan (3 kernels) ----------------
__global__ __launch_bounds__(1024) void k_scan1(const int* __restrict__ cnt,
                                                int* __restrict__ out,
                                                int* __restrict__ bsums, int N) {
    __shared__ int tmp[1024];
    int t = threadIdx.x;
    int i = blockIdx.x * 1024 + t;
    int v = (i < N) ? cnt[i] : 0;
    tmp[t] = v;
    __syncthreads();
    for (int d = 1; d < 1024; d <<= 1) {
        int x = (t >= d) ? tmp[t - d] : 0;
        __syncthreads();
        tmp[t] += x;
        __syncthreads();
    }
    if (i < N) out[i] = tmp[t] - v;              // exclusive
    if (t == 1023) bsums[blockIdx.x] = tmp[t];   // block total
}

__global__ void k_scan2(int* __restrict__ bsums, int nb) {
    __shared__ int tmp[64];
    int t = threadIdx.x;
    int v = (t < nb) ? bsums[t] : 0;
    tmp[t] = v;
    __syncthreads();
    for (int d = 1; d < 64; d <<= 1) {
        int x = (t >= d) ? tmp[t - d] : 0;
        __syncthreads();
        tmp[t] += x;
        __syncthreads();
    }
    if (t < nb) bsums[t] = tmp[t] - v;           // exclusive block offsets
}

__global__ __launch_bounds__(1024) void k_scan3(int* __restrict__ off,
                                                const int* __restrict__ bsums,
                                                int N, int E) {
    int i = blockIdx.x * 1024 + threadIdx.x;
    if (i < N) off[i] += bsums[blockIdx.x];
    if (i == 0) off[N] = E;
}

// ---------------- CSR fill (bucket by dst) ----------------
__global__ void k_fill(const int* __restrict__ src, const int* __restrict__ dst,
                       const int* __restrict__ off, int* __restrict__ cursor,
                       int* __restrict__ csr_src, int E) {
    int e = blockIdx.x * 256 + threadIdx.x;
    if (e < E) {
        int d = dst[e];
        int p = off[d] + atomicAdd(&cursor[d], 1);
        csr_src[p] = src[e];
    }
}

// ---------------- fp32 tiled GEMM: H[N,128] = X[N,K] @ W[K,128] ----------------
// BM=128, BN=128(full), BK=16; 256 threads, 8x8 micro-tile per thread.
#define BM 128
#define BK 16
__global__ __launch_bounds__(256) void k_gemm(const float* __restrict__ X,
                                              const float* __restrict__ W,
                                              float* __restrict__ H,
                                              int N, int K) {
    __shared__ float Xs[BK][BM + 4];   // transposed: Xs[k][m]
    __shared__ float Ws[BK][D_H + 4];
    const int t = threadIdx.x;
    const int tx = t & 15;             // col group: cols tx*8 .. +7
    const int ty = t >> 4;             // row group: rows ty*8 .. +7
    const int row0 = blockIdx.x * BM;

    float acc[8][8];
#pragma unroll
    for (int i = 0; i < 8; i++)
#pragma unroll
        for (int j = 0; j < 8; j++) acc[i][j] = 0.0f;

    for (int k0 = 0; k0 < K; k0 += BK) {
        // stage X tile (128 rows x 16 cols) transposed into LDS
#pragma unroll
        for (int i = 0; i < 2; i++) {
            int idx = t + i * 256;         // 0..511 = 128 rows * 4 float4
            int r   = idx >> 2;
            int c4  = idx & 3;
            int gr  = row0 + r;
            float4 v = make_float4(0.f, 0.f, 0.f, 0.f);
            if (gr < N) v = *(const float4*)(X + (size_t)gr * K + k0 + c4 * 4);
            Xs[c4 * 4 + 0][r] = v.x;
            Xs[c4 * 4 + 1][r] = v.y;
            Xs[c4 * 4 + 2][r] = v.z;
            Xs[c4 * 4 + 3][r] = v.w;
        }
        // stage W tile (16 x 128)
#pragma unroll
        for (int i = 0; i < 2; i++) {
            int idx = t + i * 256;         // 0..511 = 16 rows * 32 float4
            int r   = idx >> 5;
            int c4  = idx & 31;
            *(float4*)&Ws[r][c4 * 4] = *(const float4*)(W + (size_t)(k0 + r) * D_H + c4 * 4);
        }
        __syncthreads();

#pragma unroll
        for (int k = 0; k < BK; k++) {
            float4 a0 = *(const float4*)&Xs[k][ty * 8];
            float4 a1 = *(const float4*)&Xs[k][ty * 8 + 4];
            float4 b0 = *(const float4*)&Ws[k][tx * 8];
            float4 b1 = *(const float4*)&Ws[k][tx * 8 + 4];
            float a[8] = {a0.x, a0.y, a0.z, a0.w, a1.x, a1.y, a1.z, a1.w};
            float b[8] = {b0.x, b0.y, b0.z, b0.w, b1.x, b1.y, b1.z, b1.w};
#pragma unroll
            for (int i = 0; i < 8; i++)
#pragma unroll
                for (int j = 0; j < 8; j++) acc[i][j] = fmaf(a[i], b[j], acc[i][j]);
        }
        __syncthreads();
    }

#pragma unroll
    for (int i = 0; i < 8; i++) {
        int gr = row0 + ty * 8 + i;
        if (gr < N) {
            float4 o0 = make_float4(acc[i][0], acc[i][1], acc[i][2], acc[i][3]);
            float4 o1 = make_float4(acc[i][4], acc[i][5], acc[i][6], acc[i][7]);
            *(float4*)(H + (size_t)gr * D_H + tx * 8)     = o0;
            *(float4*)(H + (size_t)gr * D_H + tx * 8 + 4) = o1;
        }
    }
}

// ---------------- aggregation: out[i] = (relu?)(b + di*(di*H[i] + sum dis[s]*H[s])) ----
// blockDim = (128, 2): 2 nodes per block, one lane per feature.
__global__ __launch_bounds__(256) void k_agg(const float* __restrict__ H,
                                             const float* __restrict__ dis,
                                             const int* __restrict__ off,
                                             const int* __restrict__ csr_src,
                                             const float* __restrict__ bias,
                                             float* __restrict__ out,
                                             int N, int do_relu) {
    int node = blockIdx.x * 2 + threadIdx.y;
    if (node >= N) return;
    int f = threadIdx.x;
    float di  = dis[node];
    float acc = di * H[(size_t)node * D_H + f];   // self-loop term (x di at end)
    int p  = off[node];
    int p1 = off[node + 1];
    for (; p < p1; p++) {
        int s = csr_src[p];
        acc = fmaf(dis[s], H[(size_t)s * D_H + f], acc);
    }
    float v = fmaf(di, acc, bias[f]);
    if (do_relu) v = fmaxf(v, 0.0f);
    out[(size_t)node * D_H + f] = v;
}

extern "C" void kernel_launch(void* const* d_in, const int* in_sizes, int n_in,
                              void* d_out, int out_size, void* d_ws, size_t ws_size,
                              hipStream_t stream) {
    const float* X  = (const float*)d_in[0];
    const int*   ei = (const int*)d_in[1];
    const float* W1 = (const float*)d_in[2];
    const float* b1 = (const float*)d_in[3];
    const float* W2 = (const float*)d_in[4];
    const float* b2 = (const float*)d_in[5];
    float* out = (float*)d_out;

    const int N = in_sizes[0] / 256;   // 50000
    const int E = in_sizes[1] / 2;     // 800000
    const int K1 = 256;

    const int* src = ei;
    const int* dst = ei + E;

    // workspace carve-up (256B aligned)
    uintptr_t p = (uintptr_t)d_ws;
    auto carve = [&](size_t bytes) {
        uintptr_t q = p;
        p += (bytes + 255) & ~(size_t)255;
        return q;
    };
    int*   cnt   = (int*)carve((size_t)N * 4);          // also reused as fill cursor
    int*   off   = (int*)carve((size_t)(N + 1) * 4);
    int*   bsums = (int*)carve(64 * 4);
    float* dis   = (float*)carve((size_t)N * 4);
    int*   csr   = (int*)carve((size_t)E * 4);
    float* H     = (float*)carve((size_t)N * D_H * 4);
    float* X1    = (float*)carve((size_t)N * D_H * 4);

    const int nb = (N + 1023) / 1024;   // scan blocks

    hipMemsetAsync(cnt, 0, (size_t)N * 4, stream);
    k_count<<<(E + 255) / 256, 256, 0, stream>>>(dst, cnt, E);
    k_dis<<<(N + 255) / 256, 256, 0, stream>>>(cnt, dis, N);
    k_scan1<<<nb, 1024, 0, stream>>>(cnt, off, bsums, N);
    k_scan2<<<1, 64, 0, stream>>>(bsums, nb);
    k_scan3<<<nb, 1024, 0, stream>>>(off, bsums, N, E);
    hipMemsetAsync(cnt, 0, (size_t)N * 4, stream);
    k_fill<<<(E + 255) / 256, 256, 0, stream>>>(src, dst, off, cnt, csr, E);

    // layer 1: H = X @ W1 ; X1 = relu(agg(H) + b1)
    k_gemm<<<(N + BM - 1) / BM, 256, 0, stream>>>(X, W1, H, N, K1);
    k_agg<<<(N + 1) / 2, dim3(128, 2), 0, stream>>>(H, dis, off, csr, b1, X1, N, 1);

    // layer 2: H = X1 @ W2 ; out = agg(H) + b2
    k_gemm<<<(N + BM - 1) / BM, 256, 0, stream>>>(X1, W2, H, N, D_H);
    k_agg<<<(N + 1) / 2, dim3(128, 2), 0, stream>>>(H, dis, off, csr, b2, out, N, 0);
}

// Round 2
// 392.395 us; speedup vs baseline: 1.4315x; 1.4315x over previous
//
#include <hip/hip_runtime.h>
#include <hip/hip_bf16.h>
#include <stdint.h>

#define D_H 128

// ---------------- degree count ----------------
__global__ void k_count(const int* __restrict__ dst, int* __restrict__ cnt, int E) {
    int e = blockIdx.x * 256 + threadIdx.x;
    if (e < E) atomicAdd(&cnt[dst[e]], 1);
}

// dis[i] = 1/sqrt(deg_in(i) + 1)   (self-loop included; deg>=1 always)
__global__ void k_dis(const int* __restrict__ cnt, float* __restrict__ dis, int N) {
    int i = blockIdx.x * 256 + threadIdx.x;
    if (i < N) dis[i] = 1.0f / sqrtf((float)(cnt[i] + 1));
}

// ---------------- exclusive scan (3 kernels) ----------------
__global__ __launch_bounds__(1024) void k_scan1(const int* __restrict__ cnt,
                                                int* __restrict__ out,
                                                int* __restrict__ bsums, int N) {
    __shared__ int tmp[1024];
    int t = threadIdx.x;
    int i = blockIdx.x * 1024 + t;
    int v = (i < N) ? cnt[i] : 0;
    tmp[t] = v;
    __syncthreads();
    for (int d = 1; d < 1024; d <<= 1) {
        int x = (t >= d) ? tmp[t - d] : 0;
        __syncthreads();
        tmp[t] += x;
        __syncthreads();
    }
    if (i < N) out[i] = tmp[t] - v;              // exclusive
    if (t == 1023) bsums[blockIdx.x] = tmp[t];   // block total
}

__global__ void k_scan2(int* __restrict__ bsums, int nb) {
    __shared__ int tmp[64];
    int t = threadIdx.x;
    int v = (t < nb) ? bsums[t] : 0;
    tmp[t] = v;
    __syncthreads();
    for (int d = 1; d < 64; d <<= 1) {
        int x = (t >= d) ? tmp[t - d] : 0;
        __syncthreads();
        tmp[t] += x;
        __syncthreads();
    }
    if (t < nb) bsums[t] = tmp[t] - v;           // exclusive block offsets
}

__global__ __launch_bounds__(1024) void k_scan3(int* __restrict__ off,
                                                const int* __restrict__ bsums,
                                                int N, int E) {
    int i = blockIdx.x * 1024 + threadIdx.x;
    if (i < N) off[i] += bsums[blockIdx.x];
    if (i == 0) off[N] = E;
}

// ---------------- CSR fill (bucket by dst) ----------------
__global__ void k_fill(const int* __restrict__ src, const int* __restrict__ dst,
                       const int* __restrict__ off, int* __restrict__ cursor,
                       int* __restrict__ csr_src, int E) {
    int e = blockIdx.x * 256 + threadIdx.x;
    if (e < E) {
        int d = dst[e];
        int p = off[d] + atomicAdd(&cursor[d], 1);
        csr_src[p] = src[e];
    }
}

// ---------------- fp32 tiled GEMM: H[N,128] = X[N,K] @ W[K,128] ----------------
// BM=128, BN=128(full), BK=16; 256 threads, 8x8 micro-tile per thread.
#define BM 128
#define BK 16
__global__ __launch_bounds__(256) void k_gemm(const float* __restrict__ X,
                                              const float* __restrict__ W,
                                              float* __restrict__ H,
                                              int N, int K) {
    __shared__ float Xs[BK][BM + 4];   // transposed: Xs[k][m]
    __shared__ float Ws[BK][D_H + 4];
    const int t = threadIdx.x;
    const int tx = t & 15;             // col group: cols tx*8 .. +7
    const int ty = t >> 4;             // row group: rows ty*8 .. +7
    const int row0 = blockIdx.x * BM;

    float acc[8][8];
#pragma unroll
    for (int i = 0; i < 8; i++)
#pragma unroll
        for (int j = 0; j < 8; j++) acc[i][j] = 0.0f;

    for (int k0 = 0; k0 < K; k0 += BK) {
        // stage X tile (128 rows x 16 cols) transposed into LDS
#pragma unroll
        for (int i = 0; i < 2; i++) {
            int idx = t + i * 256;         // 0..511 = 128 rows * 4 float4
            int r   = idx >> 2;
            int c4  = idx & 3;
            int gr  = row0 + r;
            float4 v = make_float4(0.f, 0.f, 0.f, 0.f);
            if (gr < N) v = *(const float4*)(X + (size_t)gr * K + k0 + c4 * 4);
            Xs[c4 * 4 + 0][r] = v.x;
            Xs[c4 * 4 + 1][r] = v.y;
            Xs[c4 * 4 + 2][r] = v.z;
            Xs[c4 * 4 + 3][r] = v.w;
        }
        // stage W tile (16 x 128)
#pragma unroll
        for (int i = 0; i < 2; i++) {
            int idx = t + i * 256;         // 0..511 = 16 rows * 32 float4
            int r   = idx >> 5;
            int c4  = idx & 31;
            *(float4*)&Ws[r][c4 * 4] = *(const float4*)(W + (size_t)(k0 + r) * D_H + c4 * 4);
        }
        __syncthreads();

#pragma unroll
        for (int k = 0; k < BK; k++) {
            float4 a0 = *(const float4*)&Xs[k][ty * 8];
            float4 a1 = *(const float4*)&Xs[k][ty * 8 + 4];
            float4 b0 = *(const float4*)&Ws[k][tx * 8];
            float4 b1 = *(const float4*)&Ws[k][tx * 8 + 4];
            float a[8] = {a0.x, a0.y, a0.z, a0.w, a1.x, a1.y, a1.z, a1.w};
            float b[8] = {b0.x, b0.y, b0.z, b0.w, b1.x, b1.y, b1.z, b1.w};
#pragma unroll
            for (int i = 0; i < 8; i++)
#pragma unroll
                for (int j = 0; j < 8; j++) acc[i][j] = fmaf(a[i], b[j], acc[i][j]);
        }
        __syncthreads();
    }

#pragma unroll
    for (int i = 0; i < 8; i++) {
        int gr = row0 + ty * 8 + i;
        if (gr < N) {
            float4 o0 = make_float4(acc[i][0], acc[i][1], acc[i][2], acc[i][3]);
            float4 o1 = make_float4(acc[i][4], acc[i][5], acc[i][6], acc[i][7]);
            *(float4*)(H + (size_t)gr * D_H + tx * 8)     = o0;
            *(float4*)(H + (size_t)gr * D_H + tx * 8 + 4) = o1;
        }
    }
}

// ---------------- aggregation ----------------
// out[i] = (relu?)(b + di*(di*H[i] + sum_s dis[s]*H[s]))
// blockDim = (64, 4): 4 nodes per block, one wave (64 lanes) per node,
// each lane owns 2 consecutive features (float2). Edge loop unrolled x8
// with independent accumulators for memory-level parallelism.
__global__ __launch_bounds__(256) void k_agg(const float2* __restrict__ H2,
                                             const float* __restrict__ dis,
                                             const int* __restrict__ off,
                                             const int* __restrict__ csr_src,
                                             const float* __restrict__ bias,
                                             float2* __restrict__ out2,
                                             int N, int do_relu) {
    int node = blockIdx.x * 4 + threadIdx.y;
    if (node >= N) return;
    int f = threadIdx.x;                 // 0..63 -> features 2f, 2f+1
    float di = dis[node];
    float2 hs = H2[(size_t)node * 64 + f];
    float2 a0 = make_float2(di * hs.x, di * hs.y);
    float2 a1 = make_float2(0.f, 0.f);
    float2 a2 = make_float2(0.f, 0.f);
    float2 a3 = make_float2(0.f, 0.f);

    int p  = off[node];
    int p1 = off[node + 1];

    for (; p + 8 <= p1; p += 8) {
        int s0 = csr_src[p + 0], s1 = csr_src[p + 1];
        int s2 = csr_src[p + 2], s3 = csr_src[p + 3];
        int s4 = csr_src[p + 4], s5 = csr_src[p + 5];
        int s6 = csr_src[p + 6], s7 = csr_src[p + 7];
        float w0 = dis[s0], w1 = dis[s1], w2 = dis[s2], w3 = dis[s3];
        float w4 = dis[s4], w5 = dis[s5], w6 = dis[s6], w7 = dis[s7];
        float2 h0 = H2[(size_t)s0 * 64 + f];
        float2 h1 = H2[(size_t)s1 * 64 + f];
        float2 h2 = H2[(size_t)s2 * 64 + f];
        float2 h3 = H2[(size_t)s3 * 64 + f];
        float2 h4 = H2[(size_t)s4 * 64 + f];
        float2 h5 = H2[(size_t)s5 * 64 + f];
        float2 h6 = H2[(size_t)s6 * 64 + f];
        float2 h7 = H2[(size_t)s7 * 64 + f];
        a0.x = fmaf(w0, h0.x, a0.x); a0.y = fmaf(w0, h0.y, a0.y);
        a1.x = fmaf(w1, h1.x, a1.x); a1.y = fmaf(w1, h1.y, a1.y);
        a2.x = fmaf(w2, h2.x, a2.x); a2.y = fmaf(w2, h2.y, a2.y);
        a3.x = fmaf(w3, h3.x, a3.x); a3.y = fmaf(w3, h3.y, a3.y);
        a0.x = fmaf(w4, h4.x, a0.x); a0.y = fmaf(w4, h4.y, a0.y);
        a1.x = fmaf(w5, h5.x, a1.x); a1.y = fmaf(w5, h5.y, a1.y);
        a2.x = fmaf(w6, h6.x, a2.x); a2.y = fmaf(w6, h6.y, a2.y);
        a3.x = fmaf(w7, h7.x, a3.x); a3.y = fmaf(w7, h7.y, a3.y);
    }
    for (; p + 2 <= p1; p += 2) {
        int s0 = csr_src[p + 0], s1 = csr_src[p + 1];
        float w0 = dis[s0], w1 = dis[s1];
        float2 h0 = H2[(size_t)s0 * 64 + f];
        float2 h1 = H2[(size_t)s1 * 64 + f];
        a0.x = fmaf(w0, h0.x, a0.x); a0.y = fmaf(w0, h0.y, a0.y);
        a1.x = fmaf(w1, h1.x, a1.x); a1.y = fmaf(w1, h1.y, a1.y);
    }
    if (p < p1) {
        int s0 = csr_src[p];
        float w0 = dis[s0];
        float2 h0 = H2[(size_t)s0 * 64 + f];
        a2.x = fmaf(w0, h0.x, a2.x); a2.y = fmaf(w0, h0.y, a2.y);
    }

    float accx = (a0.x + a1.x) + (a2.x + a3.x);
    float accy = (a0.y + a1.y) + (a2.y + a3.y);
    const float2 bv = ((const float2*)bias)[f];
    float vx = fmaf(di, accx, bv.x);
    float vy = fmaf(di, accy, bv.y);
    if (do_relu) { vx = fmaxf(vx, 0.0f); vy = fmaxf(vy, 0.0f); }
    out2[(size_t)node * 64 + f] = make_float2(vx, vy);
}

extern "C" void kernel_launch(void* const* d_in, const int* in_sizes, int n_in,
                              void* d_out, int out_size, void* d_ws, size_t ws_size,
                              hipStream_t stream) {
    const float* X  = (const float*)d_in[0];
    const int*   ei = (const int*)d_in[1];
    const float* W1 = (const float*)d_in[2];
    const float* b1 = (const float*)d_in[3];
    const float* W2 = (const float*)d_in[4];
    const float* b2 = (const float*)d_in[5];
    float* out = (float*)d_out;

    const int N = in_sizes[0] / 256;   // 50000
    const int E = in_sizes[1] / 2;     // 800000
    const int K1 = 256;

    const int* src = ei;
    const int* dst = ei + E;

    // workspace carve-up (256B aligned)
    uintptr_t p = (uintptr_t)d_ws;
    auto carve = [&](size_t bytes) {
        uintptr_t q = p;
        p += (bytes + 255) & ~(size_t)255;
        return q;
    };
    int*   cnt   = (int*)carve((size_t)N * 4);          // also reused as fill cursor
    int*   off   = (int*)carve((size_t)(N + 1) * 4);
    int*   bsums = (int*)carve(64 * 4);
    float* dis   = (float*)carve((size_t)N * 4);
    int*   csr   = (int*)carve((size_t)E * 4);
    float* H     = (float*)carve((size_t)N * D_H * 4);
    float* X1    = (float*)carve((size_t)N * D_H * 4);

    const int nb = (N + 1023) / 1024;   // scan blocks

    hipMemsetAsync(cnt, 0, (size_t)N * 4, stream);
    k_count<<<(E + 255) / 256, 256, 0, stream>>>(dst, cnt, E);
    k_dis<<<(N + 255) / 256, 256, 0, stream>>>(cnt, dis, N);
    k_scan1<<<nb, 1024, 0, stream>>>(cnt, off, bsums, N);
    k_scan2<<<1, 64, 0, stream>>>(bsums, nb);
    k_scan3<<<nb, 1024, 0, stream>>>(off, bsums, N, E);
    hipMemsetAsync(cnt, 0, (size_t)N * 4, stream);
    k_fill<<<(E + 255) / 256, 256, 0, stream>>>(src, dst, off, cnt, csr, E);

    // layer 1: H = X @ W1 ; X1 = relu(agg(H) + b1)
    k_gemm<<<(N + BM - 1) / BM, 256, 0, stream>>>(X, W1, H, N, K1);
    k_agg<<<(N + 3) / 4, dim3(64, 4), 0, stream>>>((const float2*)H, dis, off, csr,
                                                   b1, (float2*)X1, N, 1);

    // layer 2: H = X1 @ W2 ; out = agg(H) + b2
    k_gemm<<<(N + BM - 1) / BM, 256, 0, stream>>>(X1, W2, H, N, D_H);
    k_agg<<<(N + 3) / 4, dim3(64, 4), 0, stream>>>((const float2*)H, dis, off, csr,
                                                   b2, (float2*)out, N, 0);
}

// Round 3
// 356.766 us; speedup vs baseline: 1.5745x; 1.0999x over previous
//
#include <hip/hip_runtime.h>
#include <hip/hip_bf16.h>
#include <stdint.h>

#define D_H 128

typedef __bf16 bf16_t;
typedef bf16_t bf16x8 __attribute__((ext_vector_type(8)));
typedef bf16_t bf16x4 __attribute__((ext_vector_type(4)));
typedef bf16_t bf16x2 __attribute__((ext_vector_type(2)));
typedef float  f32x4  __attribute__((ext_vector_type(4)));

// ---------------- degree count ----------------
__global__ void k_count(const int* __restrict__ dst, int* __restrict__ cnt, int E) {
    int e = blockIdx.x * 256 + threadIdx.x;
    if (e < E) atomicAdd(&cnt[dst[e]], 1);
}

// dis[i] = 1/sqrt(deg_in(i) + 1)
__global__ void k_dis(const int* __restrict__ cnt, float* __restrict__ dis, int N) {
    int i = blockIdx.x * 256 + threadIdx.x;
    if (i < N) dis[i] = 1.0f / sqrtf((float)(cnt[i] + 1));
}

// ---------------- exclusive scan (3 kernels) ----------------
__global__ __launch_bounds__(1024) void k_scan1(const int* __restrict__ cnt,
                                                int* __restrict__ out,
                                                int* __restrict__ bsums, int N) {
    __shared__ int tmp[1024];
    int t = threadIdx.x;
    int i = blockIdx.x * 1024 + t;
    int v = (i < N) ? cnt[i] : 0;
    tmp[t] = v;
    __syncthreads();
    for (int d = 1; d < 1024; d <<= 1) {
        int x = (t >= d) ? tmp[t - d] : 0;
        __syncthreads();
        tmp[t] += x;
        __syncthreads();
    }
    if (i < N) out[i] = tmp[t] - v;
    if (t == 1023) bsums[blockIdx.x] = tmp[t];
}

__global__ void k_scan2(int* __restrict__ bsums, int nb) {
    __shared__ int tmp[64];
    int t = threadIdx.x;
    int v = (t < nb) ? bsums[t] : 0;
    tmp[t] = v;
    __syncthreads();
    for (int d = 1; d < 64; d <<= 1) {
        int x = (t >= d) ? tmp[t - d] : 0;
        __syncthreads();
        tmp[t] += x;
        __syncthreads();
    }
    if (t < nb) bsums[t] = tmp[t] - v;
}

__global__ __launch_bounds__(1024) void k_scan3(int* __restrict__ off,
                                                const int* __restrict__ bsums,
                                                int N, int E) {
    int i = blockIdx.x * 1024 + threadIdx.x;
    if (i < N) off[i] += bsums[blockIdx.x];
    if (i == 0) off[N] = E;
}

// ---------------- CSR fill ----------------
__global__ void k_fill(const int* __restrict__ src, const int* __restrict__ dst,
                       const int* __restrict__ off, int* __restrict__ cursor,
                       int* __restrict__ csr_src, int E) {
    int e = blockIdx.x * 256 + threadIdx.x;
    if (e < E) {
        int d = dst[e];
        int p = off[d] + atomicAdd(&cursor[d], 1);
        csr_src[p] = src[e];
    }
}

// ---------------- W prep: transpose + hi/lo bf16 split ----------------
// W[k][128] fp32 -> Wh[n][K], Wl[n][K] bf16
__global__ void k_prepw(const float* __restrict__ W, bf16_t* __restrict__ Wh,
                        bf16_t* __restrict__ Wl, int K) {
    int id = blockIdx.x * 256 + threadIdx.x;   // id < K*128
    if (id >= K * 128) return;
    int k = id >> 7;
    int n = id & 127;
    float w = W[id];
    bf16_t h = (bf16_t)w;
    bf16_t l = (bf16_t)(w - (float)h);
    Wh[(size_t)n * K + k] = h;
    Wl[(size_t)n * K + k] = l;
}

// ---------------- MFMA GEMM: C[N,128] = A[N,K] @ W[K,128] ----------------
// Compensated bf16: acc += Ah*Bh + Ah*Bl + Al*Bh  (Al*Bl ~2^-16 rel, dropped).
// BM=128, BN=128(full), BK=32; 256 threads = 4 waves in 2x2 arrangement,
// each wave computes a 64x64 region = 4x4 tiles of 16x16x32 MFMA.
// Fragment layouts (HW-verified, guide §3): A/B [idx&15][(lane>>4)*8+j],
// C/D col=lane&15, row=(lane>>4)*4+reg.
#define LDK 40   // k-stride pad: bank group (r*20 + q*4) % 32 -> 2-way max (free)
__global__ __launch_bounds__(256) void k_mm(const float* __restrict__ Af,
                                            const bf16_t* __restrict__ Ah,
                                            const bf16_t* __restrict__ Al,
                                            const bf16_t* __restrict__ Wh,
                                            const bf16_t* __restrict__ Wl,
                                            float* __restrict__ C,
                                            int N, int K, int a_fp32) {
    __shared__ bf16_t AsH[128][LDK];
    __shared__ bf16_t AsL[128][LDK];
    __shared__ bf16_t BsH[128][LDK];
    __shared__ bf16_t BsL[128][LDK];

    const int t    = threadIdx.x;
    const int lane = t & 63;
    const int wave = t >> 6;
    const int row0 = blockIdx.x * 128;
    const int wm   = (wave & 1) * 64;   // wave's m offset
    const int wn   = (wave >> 1) * 64;  // wave's n offset
    const int fm   = lane & 15;
    const int fq   = lane >> 4;

    f32x4 acc[4][4] = {};

    for (int k0 = 0; k0 < K; k0 += 32) {
        __syncthreads();   // previous-iter frag reads done before restaging
        if (a_fp32) {
            // 128 rows x 32 k fp32 = 1024 float4; 4 per thread, split to hi/lo
#pragma unroll
            for (int i = 0; i < 4; i++) {
                int idx = t + i * 256;      // 0..1023
                int r   = idx >> 3;         // 8 float4 per row
                int c4  = idx & 7;
                int gr  = row0 + r;
                float4 v = make_float4(0.f, 0.f, 0.f, 0.f);
                if (gr < N) v = *(const float4*)(Af + (size_t)gr * K + k0 + c4 * 4);
                bf16_t h0 = (bf16_t)v.x, h1 = (bf16_t)v.y, h2 = (bf16_t)v.z, h3 = (bf16_t)v.w;
                bf16_t l0 = (bf16_t)(v.x - (float)h0);
                bf16_t l1 = (bf16_t)(v.y - (float)h1);
                bf16_t l2 = (bf16_t)(v.z - (float)h2);
                bf16_t l3 = (bf16_t)(v.w - (float)h3);
                *(bf16x4*)&AsH[r][c4 * 4] = (bf16x4){h0, h1, h2, h3};
                *(bf16x4*)&AsL[r][c4 * 4] = (bf16x4){l0, l1, l2, l3};
            }
        } else {
            // 128 rows x 32 k bf16: 512 bf16x8 per array; 2 per thread each
#pragma unroll
            for (int i = 0; i < 2; i++) {
                int idx = t + i * 256;      // 0..511
                int r   = idx >> 2;         // 4 bf16x8 per row
                int c8  = idx & 3;
                int gr  = row0 + r;
                bf16x8 vh = {}, vl = {};
                if (gr < N) {
                    vh = *(const bf16x8*)(Ah + (size_t)gr * K + k0 + c8 * 8);
                    vl = *(const bf16x8*)(Al + (size_t)gr * K + k0 + c8 * 8);
                }
                *(bf16x8*)&AsH[r][c8 * 8] = vh;
                *(bf16x8*)&AsL[r][c8 * 8] = vl;
            }
        }
        // stage B: Wh/Wl[n][K] -> 128 n x 32 k
#pragma unroll
        for (int i = 0; i < 2; i++) {
            int idx = t + i * 256;
            int r   = idx >> 2;
            int c8  = idx & 3;
            *(bf16x8*)&BsH[r][c8 * 8] = *(const bf16x8*)(Wh + (size_t)r * K + k0 + c8 * 8);
            *(bf16x8*)&BsL[r][c8 * 8] = *(const bf16x8*)(Wl + (size_t)r * K + k0 + c8 * 8);
        }
        __syncthreads();

        bf16x8 ah[4], al[4], bh[4], bl[4];
#pragma unroll
        for (int i = 0; i < 4; i++) {
            ah[i] = *(const bf16x8*)&AsH[wm + i * 16 + fm][fq * 8];
            al[i] = *(const bf16x8*)&AsL[wm + i * 16 + fm][fq * 8];
            bh[i] = *(const bf16x8*)&BsH[wn + i * 16 + fm][fq * 8];
            bl[i] = *(const bf16x8*)&BsL[wn + i * 16 + fm][fq * 8];
        }
#pragma unroll
        for (int mi = 0; mi < 4; mi++)
#pragma unroll
            for (int ni = 0; ni < 4; ni++) {
                acc[mi][ni] = __builtin_amdgcn_mfma_f32_16x16x32_bf16(ah[mi], bh[ni], acc[mi][ni], 0, 0, 0);
                acc[mi][ni] = __builtin_amdgcn_mfma_f32_16x16x32_bf16(ah[mi], bl[ni], acc[mi][ni], 0, 0, 0);
                acc[mi][ni] = __builtin_amdgcn_mfma_f32_16x16x32_bf16(al[mi], bh[ni], acc[mi][ni], 0, 0, 0);
            }
    }

    // epilogue: C/D layout col=fm, row=fq*4+reg
#pragma unroll
    for (int mi = 0; mi < 4; mi++)
#pragma unroll
        for (int r = 0; r < 4; r++) {
            int grow = row0 + wm + mi * 16 + fq * 4 + r;
            if (grow < N) {
#pragma unroll
                for (int ni = 0; ni < 4; ni++)
                    C[(size_t)grow * D_H + wn + ni * 16 + fm] = acc[mi][ni][r];
            }
        }
}

// ---------------- aggregation ----------------
// out[i] = (relu?)(b + di*(di*H[i] + sum_s dis[s]*H[s]))
// One wave (64 lanes) per node, lane owns 2 features. Edge loop unrolled x8.
// mode 0: fp32 out; mode 1: relu + bf16 hi/lo pair out (feeds k_mm layer 2).
__global__ __launch_bounds__(256) void k_agg(const float2* __restrict__ H2,
                                             const float* __restrict__ dis,
                                             const int* __restrict__ off,
                                             const int* __restrict__ csr_src,
                                             const float* __restrict__ bias,
                                             float2* __restrict__ outF,
                                             bf16_t* __restrict__ outH,
                                             bf16_t* __restrict__ outL,
                                             int N, int mode) {
    int node = blockIdx.x * 4 + threadIdx.y;
    if (node >= N) return;
    int f = threadIdx.x;                 // features 2f, 2f+1
    float di = dis[node];
    float2 hs = H2[(size_t)node * 64 + f];
    float2 a0 = make_float2(di * hs.x, di * hs.y);
    float2 a1 = make_float2(0.f, 0.f);
    float2 a2 = make_float2(0.f, 0.f);
    float2 a3 = make_float2(0.f, 0.f);

    int p  = off[node];
    int p1 = off[node + 1];

    for (; p + 8 <= p1; p += 8) {
        int s0 = csr_src[p + 0], s1 = csr_src[p + 1];
        int s2 = csr_src[p + 2], s3 = csr_src[p + 3];
        int s4 = csr_src[p + 4], s5 = csr_src[p + 5];
        int s6 = csr_src[p + 6], s7 = csr_src[p + 7];
        float w0 = dis[s0], w1 = dis[s1], w2 = dis[s2], w3 = dis[s3];
        float w4 = dis[s4], w5 = dis[s5], w6 = dis[s6], w7 = dis[s7];
        float2 h0 = H2[(size_t)s0 * 64 + f];
        float2 h1 = H2[(size_t)s1 * 64 + f];
        float2 h2 = H2[(size_t)s2 * 64 + f];
        float2 h3 = H2[(size_t)s3 * 64 + f];
        float2 h4 = H2[(size_t)s4 * 64 + f];
        float2 h5 = H2[(size_t)s5 * 64 + f];
        float2 h6 = H2[(size_t)s6 * 64 + f];
        float2 h7 = H2[(size_t)s7 * 64 + f];
        a0.x = fmaf(w0, h0.x, a0.x); a0.y = fmaf(w0, h0.y, a0.y);
        a1.x = fmaf(w1, h1.x, a1.x); a1.y = fmaf(w1, h1.y, a1.y);
        a2.x = fmaf(w2, h2.x, a2.x); a2.y = fmaf(w2, h2.y, a2.y);
        a3.x = fmaf(w3, h3.x, a3.x); a3.y = fmaf(w3, h3.y, a3.y);
        a0.x = fmaf(w4, h4.x, a0.x); a0.y = fmaf(w4, h4.y, a0.y);
        a1.x = fmaf(w5, h5.x, a1.x); a1.y = fmaf(w5, h5.y, a1.y);
        a2.x = fmaf(w6, h6.x, a2.x); a2.y = fmaf(w6, h6.y, a2.y);
        a3.x = fmaf(w7, h7.x, a3.x); a3.y = fmaf(w7, h7.y, a3.y);
    }
    for (; p + 2 <= p1; p += 2) {
        int s0 = csr_src[p + 0], s1 = csr_src[p + 1];
        float w0 = dis[s0], w1 = dis[s1];
        float2 h0 = H2[(size_t)s0 * 64 + f];
        float2 h1 = H2[(size_t)s1 * 64 + f];
        a0.x = fmaf(w0, h0.x, a0.x); a0.y = fmaf(w0, h0.y, a0.y);
        a1.x = fmaf(w1, h1.x, a1.x); a1.y = fmaf(w1, h1.y, a1.y);
    }
    if (p < p1) {
        int s0 = csr_src[p];
        float w0 = dis[s0];
        float2 h0 = H2[(size_t)s0 * 64 + f];
        a2.x = fmaf(w0, h0.x, a2.x); a2.y = fmaf(w0, h0.y, a2.y);
    }

    float accx = (a0.x + a1.x) + (a2.x + a3.x);
    float accy = (a0.y + a1.y) + (a2.y + a3.y);
    const float2 bv = ((const float2*)bias)[f];
    float vx = fmaf(di, accx, bv.x);
    float vy = fmaf(di, accy, bv.y);
    if (mode == 1) {
        vx = fmaxf(vx, 0.0f);
        vy = fmaxf(vy, 0.0f);
        bf16_t hx = (bf16_t)vx, hy = (bf16_t)vy;
        bf16_t lx = (bf16_t)(vx - (float)hx);
        bf16_t ly = (bf16_t)(vy - (float)hy);
        *(bf16x2*)(outH + (size_t)node * D_H + 2 * f) = (bf16x2){hx, hy};
        *(bf16x2*)(outL + (size_t)node * D_H + 2 * f) = (bf16x2){lx, ly};
    } else {
        outF[(size_t)node * 64 + f] = make_float2(vx, vy);
    }
}

extern "C" void kernel_launch(void* const* d_in, const int* in_sizes, int n_in,
                              void* d_out, int out_size, void* d_ws, size_t ws_size,
                              hipStream_t stream) {
    const float* X  = (const float*)d_in[0];
    const int*   ei = (const int*)d_in[1];
    const float* W1 = (const float*)d_in[2];
    const float* b1 = (const float*)d_in[3];
    const float* W2 = (const float*)d_in[4];
    const float* b2 = (const float*)d_in[5];
    float* out = (float*)d_out;

    const int N  = in_sizes[0] / 256;   // 50000
    const int E  = in_sizes[1] / 2;     // 800000
    const int K1 = 256;

    const int* src = ei;
    const int* dst = ei + E;

    uintptr_t p = (uintptr_t)d_ws;
    auto carve = [&](size_t bytes) {
        uintptr_t q = p;
        p += (bytes + 255) & ~(size_t)255;
        return q;
    };
    int*    cnt   = (int*)carve((size_t)N * 4);
    int*    off   = (int*)carve((size_t)(N + 1) * 4);
    int*    bsums = (int*)carve(64 * 4);
    float*  dis   = (float*)carve((size_t)N * 4);
    int*    csr   = (int*)carve((size_t)E * 4);
    float*  H     = (float*)carve((size_t)N * D_H * 4);
    bf16_t* X1h   = (bf16_t*)carve((size_t)N * D_H * 2);
    bf16_t* X1l   = (bf16_t*)carve((size_t)N * D_H * 2);
    bf16_t* W1h   = (bf16_t*)carve((size_t)K1 * D_H * 2);
    bf16_t* W1l   = (bf16_t*)carve((size_t)K1 * D_H * 2);
    bf16_t* W2h   = (bf16_t*)carve((size_t)D_H * D_H * 2);
    bf16_t* W2l   = (bf16_t*)carve((size_t)D_H * D_H * 2);

    const int nb = (N + 1023) / 1024;

    // weight prep (tiny)
    k_prepw<<<(K1 * 128 + 255) / 256, 256, 0, stream>>>(W1, W1h, W1l, K1);
    k_prepw<<<(D_H * 128 + 255) / 256, 256, 0, stream>>>(W2, W2h, W2l, D_H);

    // graph preprocessing
    hipMemsetAsync(cnt, 0, (size_t)N * 4, stream);
    k_count<<<(E + 255) / 256, 256, 0, stream>>>(dst, cnt, E);
    k_dis<<<(N + 255) / 256, 256, 0, stream>>>(cnt, dis, N);
    k_scan1<<<nb, 1024, 0, stream>>>(cnt, off, bsums, N);
    k_scan2<<<1, 64, 0, stream>>>(bsums, nb);
    k_scan3<<<nb, 1024, 0, stream>>>(off, bsums, N, E);
    hipMemsetAsync(cnt, 0, (size_t)N * 4, stream);
    k_fill<<<(E + 255) / 256, 256, 0, stream>>>(src, dst, off, cnt, csr, E);

    const int gmm = (N + 127) / 128;

    // layer 1: H = X @ W1 (compensated bf16 MFMA); X1 = relu(agg(H)+b1) -> hi/lo bf16
    k_mm<<<gmm, 256, 0, stream>>>(X, nullptr, nullptr, W1h, W1l, H, N, K1, 1);
    k_agg<<<(N + 3) / 4, dim3(64, 4), 0, stream>>>((const float2*)H, dis, off, csr,
                                                   b1, nullptr, X1h, X1l, N, 1);

    // layer 2: H = X1 @ W2 ; out = agg(H) + b2
    k_mm<<<gmm, 256, 0, stream>>>(nullptr, X1h, X1l, W2h, W2l, H, N, D_H, 0);
    k_agg<<<(N + 3) / 4, dim3(64, 4), 0, stream>>>((const float2*)H, dis, off, csr,
                                                   b2, (float2*)out, nullptr, nullptr, N, 0);
}

// Round 4
// 354.062 us; speedup vs baseline: 1.5865x; 1.0076x over previous
//
#include <hip/hip_runtime.h>
#include <hip/hip_bf16.h>
#include <stdint.h>

#define D_H 128

typedef __bf16 bf16_t;
typedef bf16_t bf16x8 __attribute__((ext_vector_type(8)));
typedef bf16_t bf16x4 __attribute__((ext_vector_type(4)));
typedef bf16_t bf16x2 __attribute__((ext_vector_type(2)));
typedef float  f32x4  __attribute__((ext_vector_type(4)));

// ---------------- degree count ----------------
__global__ void k_count(const int* __restrict__ dst, int* __restrict__ cnt, int E) {
    int e = blockIdx.x * 256 + threadIdx.x;
    if (e < E) atomicAdd(&cnt[dst[e]], 1);
}

// dis[i] = 1/sqrt(deg_in(i) + 1)
__global__ void k_dis(const int* __restrict__ cnt, float* __restrict__ dis, int N) {
    int i = blockIdx.x * 256 + threadIdx.x;
    if (i < N) dis[i] = 1.0f / sqrtf((float)(cnt[i] + 1));
}

// ---------------- exclusive scan (3 kernels) ----------------
__global__ __launch_bounds__(1024) void k_scan1(const int* __restrict__ cnt,
                                                int* __restrict__ out,
                                                int* __restrict__ bsums, int N) {
    __shared__ int tmp[1024];
    int t = threadIdx.x;
    int i = blockIdx.x * 1024 + t;
    int v = (i < N) ? cnt[i] : 0;
    tmp[t] = v;
    __syncthreads();
    for (int d = 1; d < 1024; d <<= 1) {
        int x = (t >= d) ? tmp[t - d] : 0;
        __syncthreads();
        tmp[t] += x;
        __syncthreads();
    }
    if (i < N) out[i] = tmp[t] - v;
    if (t == 1023) bsums[blockIdx.x] = tmp[t];
}

__global__ void k_scan2(int* __restrict__ bsums, int nb) {
    __shared__ int tmp[64];
    int t = threadIdx.x;
    int v = (t < nb) ? bsums[t] : 0;
    tmp[t] = v;
    __syncthreads();
    for (int d = 1; d < 64; d <<= 1) {
        int x = (t >= d) ? tmp[t - d] : 0;
        __syncthreads();
        tmp[t] += x;
        __syncthreads();
    }
    if (t < nb) bsums[t] = tmp[t] - v;
}

__global__ __launch_bounds__(1024) void k_scan3(int* __restrict__ off,
                                                const int* __restrict__ bsums,
                                                int N, int E) {
    int i = blockIdx.x * 1024 + threadIdx.x;
    if (i < N) off[i] += bsums[blockIdx.x];
    if (i == 0) off[N] = E;
}

// ---------------- CSR fill ----------------
__global__ void k_fill(const int* __restrict__ src, const int* __restrict__ dst,
                       const int* __restrict__ off, int* __restrict__ cursor,
                       int* __restrict__ csr_src, int E) {
    int e = blockIdx.x * 256 + threadIdx.x;
    if (e < E) {
        int d = dst[e];
        int p = off[d] + atomicAdd(&cursor[d], 1);
        csr_src[p] = src[e];
    }
}

// ---------------- W prep: transpose + hi/lo bf16 split ----------------
__global__ void k_prepw(const float* __restrict__ W, bf16_t* __restrict__ Wh,
                        bf16_t* __restrict__ Wl, int K) {
    int id = blockIdx.x * 256 + threadIdx.x;   // id < K*128
    if (id >= K * 128) return;
    int k = id >> 7;
    int n = id & 127;
    float w = W[id];
    bf16_t h = (bf16_t)w;
    bf16_t l = (bf16_t)(w - (float)h);
    Wh[(size_t)n * K + k] = h;
    Wl[(size_t)n * K + k] = l;
}

// ---------------- MFMA GEMM: C[N,128] = dis[i] * (A[N,K] @ W[K,128]) -------
// Compensated bf16: acc += Ah*Bh + Ah*Bl + Al*Bh.
// BM=128, BN=128(full), BK=32; 256 threads = 4 waves (2x2), 64x64 per wave.
#define LDK 40
__global__ __launch_bounds__(256) void k_mm(const float* __restrict__ Af,
                                            const bf16_t* __restrict__ Ah,
                                            const bf16_t* __restrict__ Al,
                                            const bf16_t* __restrict__ Wh,
                                            const bf16_t* __restrict__ Wl,
                                            const float* __restrict__ dis,
                                            float* __restrict__ C,
                                            int N, int K, int a_fp32) {
    __shared__ bf16_t AsH[128][LDK];
    __shared__ bf16_t AsL[128][LDK];
    __shared__ bf16_t BsH[128][LDK];
    __shared__ bf16_t BsL[128][LDK];

    const int t    = threadIdx.x;
    const int lane = t & 63;
    const int wave = t >> 6;
    const int row0 = blockIdx.x * 128;
    const int wm   = (wave & 1) * 64;
    const int wn   = (wave >> 1) * 64;
    const int fm   = lane & 15;
    const int fq   = lane >> 4;

    f32x4 acc[4][4] = {};

    for (int k0 = 0; k0 < K; k0 += 32) {
        __syncthreads();
        if (a_fp32) {
#pragma unroll
            for (int i = 0; i < 4; i++) {
                int idx = t + i * 256;
                int r   = idx >> 3;
                int c4  = idx & 7;
                int gr  = row0 + r;
                float4 v = make_float4(0.f, 0.f, 0.f, 0.f);
                if (gr < N) v = *(const float4*)(Af + (size_t)gr * K + k0 + c4 * 4);
                bf16_t h0 = (bf16_t)v.x, h1 = (bf16_t)v.y, h2 = (bf16_t)v.z, h3 = (bf16_t)v.w;
                bf16_t l0 = (bf16_t)(v.x - (float)h0);
                bf16_t l1 = (bf16_t)(v.y - (float)h1);
                bf16_t l2 = (bf16_t)(v.z - (float)h2);
                bf16_t l3 = (bf16_t)(v.w - (float)h3);
                *(bf16x4*)&AsH[r][c4 * 4] = (bf16x4){h0, h1, h2, h3};
                *(bf16x4*)&AsL[r][c4 * 4] = (bf16x4){l0, l1, l2, l3};
            }
        } else {
#pragma unroll
            for (int i = 0; i < 2; i++) {
                int idx = t + i * 256;
                int r   = idx >> 2;
                int c8  = idx & 3;
                int gr  = row0 + r;
                bf16x8 vh = {}, vl = {};
                if (gr < N) {
                    vh = *(const bf16x8*)(Ah + (size_t)gr * K + k0 + c8 * 8);
                    vl = *(const bf16x8*)(Al + (size_t)gr * K + k0 + c8 * 8);
                }
                *(bf16x8*)&AsH[r][c8 * 8] = vh;
                *(bf16x8*)&AsL[r][c8 * 8] = vl;
            }
        }
#pragma unroll
        for (int i = 0; i < 2; i++) {
            int idx = t + i * 256;
            int r   = idx >> 2;
            int c8  = idx & 3;
            *(bf16x8*)&BsH[r][c8 * 8] = *(const bf16x8*)(Wh + (size_t)r * K + k0 + c8 * 8);
            *(bf16x8*)&BsL[r][c8 * 8] = *(const bf16x8*)(Wl + (size_t)r * K + k0 + c8 * 8);
        }
        __syncthreads();

        bf16x8 ah[4], al[4], bh[4], bl[4];
#pragma unroll
        for (int i = 0; i < 4; i++) {
            ah[i] = *(const bf16x8*)&AsH[wm + i * 16 + fm][fq * 8];
            al[i] = *(const bf16x8*)&AsL[wm + i * 16 + fm][fq * 8];
            bh[i] = *(const bf16x8*)&BsH[wn + i * 16 + fm][fq * 8];
            bl[i] = *(const bf16x8*)&BsL[wn + i * 16 + fm][fq * 8];
        }
#pragma unroll
        for (int mi = 0; mi < 4; mi++)
#pragma unroll
            for (int ni = 0; ni < 4; ni++) {
                acc[mi][ni] = __builtin_amdgcn_mfma_f32_16x16x32_bf16(ah[mi], bh[ni], acc[mi][ni], 0, 0, 0);
                acc[mi][ni] = __builtin_amdgcn_mfma_f32_16x16x32_bf16(ah[mi], bl[ni], acc[mi][ni], 0, 0, 0);
                acc[mi][ni] = __builtin_amdgcn_mfma_f32_16x16x32_bf16(al[mi], bh[ni], acc[mi][ni], 0, 0, 0);
            }
    }

    // epilogue: C/D layout col=fm, row=fq*4+reg; scale row by dis[row]
#pragma unroll
    for (int mi = 0; mi < 4; mi++)
#pragma unroll
        for (int r = 0; r < 4; r++) {
            int grow = row0 + wm + mi * 16 + fq * 4 + r;
            if (grow < N) {
                float dr = dis[grow];
#pragma unroll
                for (int ni = 0; ni < 4; ni++)
                    C[(size_t)grow * D_H + wn + ni * 16 + fm] = dr * acc[mi][ni][r];
            }
        }
}

// ---------------- aggregation ----------------
// Input Hp = dis-scaled rows H'. out[i] = (relu?)(b + di*(H'[i] + sum_s H'[s]))
// 32 lanes per node (float4/lane), 2 nodes per wave, 8 nodes per 256-block.
// Edge loop unrolled x8 with 8 independent float4 accumulators.
__global__ __launch_bounds__(256) void k_agg(const float4* __restrict__ Hp4,
                                             const float* __restrict__ dis,
                                             const int* __restrict__ off,
                                             const int* __restrict__ csr_src,
                                             const float4* __restrict__ bias4,
                                             float4* __restrict__ outF,
                                             bf16_t* __restrict__ outH,
                                             bf16_t* __restrict__ outL,
                                             int N, int mode) {
    const int half = threadIdx.x >> 5;           // 0..7: node slot in block
    const int lane = threadIdx.x & 31;           // feature group (4 floats)
    const int node = blockIdx.x * 8 + half;
    if (node >= N) return;

    float4 a0 = Hp4[(size_t)node * 32 + lane];   // self term H'[node]
    float4 a1 = {0,0,0,0}, a2 = {0,0,0,0}, a3 = {0,0,0,0};
    float4 a4 = {0,0,0,0}, a5 = {0,0,0,0}, a6 = {0,0,0,0}, a7 = {0,0,0,0};

    int p  = off[node];
    int p1 = off[node + 1];

    for (; p + 8 <= p1; p += 8) {
        int s0 = csr_src[p + 0], s1 = csr_src[p + 1];
        int s2 = csr_src[p + 2], s3 = csr_src[p + 3];
        int s4 = csr_src[p + 4], s5 = csr_src[p + 5];
        int s6 = csr_src[p + 6], s7 = csr_src[p + 7];
        float4 h0 = Hp4[(size_t)s0 * 32 + lane];
        float4 h1 = Hp4[(size_t)s1 * 32 + lane];
        float4 h2 = Hp4[(size_t)s2 * 32 + lane];
        float4 h3 = Hp4[(size_t)s3 * 32 + lane];
        float4 h4 = Hp4[(size_t)s4 * 32 + lane];
        float4 h5 = Hp4[(size_t)s5 * 32 + lane];
        float4 h6 = Hp4[(size_t)s6 * 32 + lane];
        float4 h7 = Hp4[(size_t)s7 * 32 + lane];
        a0.x += h0.x; a0.y += h0.y; a0.z += h0.z; a0.w += h0.w;
        a1.x += h1.x; a1.y += h1.y; a1.z += h1.z; a1.w += h1.w;
        a2.x += h2.x; a2.y += h2.y; a2.z += h2.z; a2.w += h2.w;
        a3.x += h3.x; a3.y += h3.y; a3.z += h3.z; a3.w += h3.w;
        a4.x += h4.x; a4.y += h4.y; a4.z += h4.z; a4.w += h4.w;
        a5.x += h5.x; a5.y += h5.y; a5.z += h5.z; a5.w += h5.w;
        a6.x += h6.x; a6.y += h6.y; a6.z += h6.z; a6.w += h6.w;
        a7.x += h7.x; a7.y += h7.y; a7.z += h7.z; a7.w += h7.w;
    }
    if (p + 4 <= p1) {
        int s0 = csr_src[p + 0], s1 = csr_src[p + 1];
        int s2 = csr_src[p + 2], s3 = csr_src[p + 3];
        float4 h0 = Hp4[(size_t)s0 * 32 + lane];
        float4 h1 = Hp4[(size_t)s1 * 32 + lane];
        float4 h2 = Hp4[(size_t)s2 * 32 + lane];
        float4 h3 = Hp4[(size_t)s3 * 32 + lane];
        a0.x += h0.x; a0.y += h0.y; a0.z += h0.z; a0.w += h0.w;
        a1.x += h1.x; a1.y += h1.y; a1.z += h1.z; a1.w += h1.w;
        a2.x += h2.x; a2.y += h2.y; a2.z += h2.z; a2.w += h2.w;
        a3.x += h3.x; a3.y += h3.y; a3.z += h3.z; a3.w += h3.w;
        p += 4;
    }
    for (; p < p1; p++) {
        int s0 = csr_src[p];
        float4 h0 = Hp4[(size_t)s0 * 32 + lane];
        a0.x += h0.x; a0.y += h0.y; a0.z += h0.z; a0.w += h0.w;
    }

    float4 s01, s23, s45, s67, sA, sB, sum;
    s01.x = a0.x + a1.x; s01.y = a0.y + a1.y; s01.z = a0.z + a1.z; s01.w = a0.w + a1.w;
    s23.x = a2.x + a3.x; s23.y = a2.y + a3.y; s23.z = a2.z + a3.z; s23.w = a2.w + a3.w;
    s45.x = a4.x + a5.x; s45.y = a4.y + a5.y; s45.z = a4.z + a5.z; s45.w = a4.w + a5.w;
    s67.x = a6.x + a7.x; s67.y = a6.y + a7.y; s67.z = a6.z + a7.z; s67.w = a6.w + a7.w;
    sA.x = s01.x + s23.x; sA.y = s01.y + s23.y; sA.z = s01.z + s23.z; sA.w = s01.w + s23.w;
    sB.x = s45.x + s67.x; sB.y = s45.y + s67.y; sB.z = s45.z + s67.z; sB.w = s45.w + s67.w;
    sum.x = sA.x + sB.x; sum.y = sA.y + sB.y; sum.z = sA.z + sB.z; sum.w = sA.w + sB.w;

    const float  di = dis[node];
    const float4 bv = bias4[lane];
    float vx = fmaf(di, sum.x, bv.x);
    float vy = fmaf(di, sum.y, bv.y);
    float vz = fmaf(di, sum.z, bv.z);
    float vw = fmaf(di, sum.w, bv.w);

    if (mode == 1) {
        vx = fmaxf(vx, 0.0f); vy = fmaxf(vy, 0.0f);
        vz = fmaxf(vz, 0.0f); vw = fmaxf(vw, 0.0f);
        bf16_t hx = (bf16_t)vx, hy = (bf16_t)vy, hz = (bf16_t)vz, hw = (bf16_t)vw;
        bf16_t lx = (bf16_t)(vx - (float)hx);
        bf16_t ly = (bf16_t)(vy - (float)hy);
        bf16_t lz = (bf16_t)(vz - (float)hz);
        bf16_t lw = (bf16_t)(vw - (float)hw);
        *(bf16x4*)(outH + (size_t)node * D_H + 4 * lane) = (bf16x4){hx, hy, hz, hw};
        *(bf16x4*)(outL + (size_t)node * D_H + 4 * lane) = (bf16x4){lx, ly, lz, lw};
    } else {
        outF[(size_t)node * 32 + lane] = make_float4(vx, vy, vz, vw);
    }
}

extern "C" void kernel_launch(void* const* d_in, const int* in_sizes, int n_in,
                              void* d_out, int out_size, void* d_ws, size_t ws_size,
                              hipStream_t stream) {
    const float* X  = (const float*)d_in[0];
    const int*   ei = (const int*)d_in[1];
    const float* W1 = (const float*)d_in[2];
    const float* b1 = (const float*)d_in[3];
    const float* W2 = (const float*)d_in[4];
    const float* b2 = (const float*)d_in[5];
    float* out = (float*)d_out;

    const int N  = in_sizes[0] / 256;   // 50000
    const int E  = in_sizes[1] / 2;     // 800000
    const int K1 = 256;

    const int* src = ei;
    const int* dst = ei + E;

    uintptr_t p = (uintptr_t)d_ws;
    auto carve = [&](size_t bytes) {
        uintptr_t q = p;
        p += (bytes + 255) & ~(size_t)255;
        return q;
    };
    int*    cnt   = (int*)carve((size_t)N * 4);
    int*    off   = (int*)carve((size_t)(N + 1) * 4);
    int*    bsums = (int*)carve(64 * 4);
    float*  dis   = (float*)carve((size_t)N * 4);
    int*    csr   = (int*)carve((size_t)E * 4);
    float*  H     = (float*)carve((size_t)N * D_H * 4);
    bf16_t* X1h   = (bf16_t*)carve((size_t)N * D_H * 2);
    bf16_t* X1l   = (bf16_t*)carve((size_t)N * D_H * 2);
    bf16_t* W1h   = (bf16_t*)carve((size_t)K1 * D_H * 2);
    bf16_t* W1l   = (bf16_t*)carve((size_t)K1 * D_H * 2);
    bf16_t* W2h   = (bf16_t*)carve((size_t)D_H * D_H * 2);
    bf16_t* W2l   = (bf16_t*)carve((size_t)D_H * D_H * 2);

    const int nb = (N + 1023) / 1024;

    // weight prep (tiny)
    k_prepw<<<(K1 * 128 + 255) / 256, 256, 0, stream>>>(W1, W1h, W1l, K1);
    k_prepw<<<(D_H * 128 + 255) / 256, 256, 0, stream>>>(W2, W2h, W2l, D_H);

    // graph preprocessing
    hipMemsetAsync(cnt, 0, (size_t)N * 4, stream);
    k_count<<<(E + 255) / 256, 256, 0, stream>>>(dst, cnt, E);
    k_dis<<<(N + 255) / 256, 256, 0, stream>>>(cnt, dis, N);
    k_scan1<<<nb, 1024, 0, stream>>>(cnt, off, bsums, N);
    k_scan2<<<1, 64, 0, stream>>>(bsums, nb);
    k_scan3<<<nb, 1024, 0, stream>>>(off, bsums, N, E);
    hipMemsetAsync(cnt, 0, (size_t)N * 4, stream);
    k_fill<<<(E + 255) / 256, 256, 0, stream>>>(src, dst, off, cnt, csr, E);

    const int gmm = (N + 127) / 128;
    const int gag = (N + 7) / 8;

    // layer 1: H' = dis .* (X @ W1); X1 = relu(agg(H')+b1) -> hi/lo bf16
    k_mm<<<gmm, 256, 0, stream>>>(X, nullptr, nullptr, W1h, W1l, dis, H, N, K1, 1);
    k_agg<<<gag, 256, 0, stream>>>((const float4*)H, dis, off, csr,
                                   (const float4*)b1, nullptr, X1h, X1l, N, 1);

    // layer 2: H' = dis .* (X1 @ W2); out = agg(H') + b2
    k_mm<<<gmm, 256, 0, stream>>>(nullptr, X1h, X1l, W2h, W2l, dis, H, N, D_H, 0);
    k_agg<<<gag, 256, 0, stream>>>((const float4*)H, dis, off, csr,
                                   (const float4*)b2, (float4*)out, nullptr, nullptr, N, 0);
}

// Round 5
// 308.261 us; speedup vs baseline: 1.8222x; 1.1486x over previous
//
#include <hip/hip_runtime.h>
#include <hip/hip_bf16.h>
#include <stdint.h>

#define D_H 128

typedef __bf16 bf16_t;
typedef bf16_t bf16x8 __attribute__((ext_vector_type(8)));
typedef bf16_t bf16x4 __attribute__((ext_vector_type(4)));
typedef bf16_t bf16x2 __attribute__((ext_vector_type(2)));
typedef float  f32x4  __attribute__((ext_vector_type(4)));

// ---------------- degree count ----------------
__global__ void k_count(const int* __restrict__ dst, int* __restrict__ cnt, int E) {
    int e = blockIdx.x * 256 + threadIdx.x;
    if (e < E) atomicAdd(&cnt[dst[e]], 1);
}

// dis[i] = 1/sqrt(deg_in(i) + 1)
__global__ void k_dis(const int* __restrict__ cnt, float* __restrict__ dis, int N) {
    int i = blockIdx.x * 256 + threadIdx.x;
    if (i < N) dis[i] = 1.0f / sqrtf((float)(cnt[i] + 1));
}

// ---------------- exclusive scan (3 kernels) ----------------
__global__ __launch_bounds__(1024) void k_scan1(const int* __restrict__ cnt,
                                                int* __restrict__ out,
                                                int* __restrict__ bsums, int N) {
    __shared__ int tmp[1024];
    int t = threadIdx.x;
    int i = blockIdx.x * 1024 + t;
    int v = (i < N) ? cnt[i] : 0;
    tmp[t] = v;
    __syncthreads();
    for (int d = 1; d < 1024; d <<= 1) {
        int x = (t >= d) ? tmp[t - d] : 0;
        __syncthreads();
        tmp[t] += x;
        __syncthreads();
    }
    if (i < N) out[i] = tmp[t] - v;
    if (t == 1023) bsums[blockIdx.x] = tmp[t];
}

__global__ void k_scan2(int* __restrict__ bsums, int nb) {
    __shared__ int tmp[64];
    int t = threadIdx.x;
    int v = (t < nb) ? bsums[t] : 0;
    tmp[t] = v;
    __syncthreads();
    for (int d = 1; d < 64; d <<= 1) {
        int x = (t >= d) ? tmp[t - d] : 0;
        __syncthreads();
        tmp[t] += x;
        __syncthreads();
    }
    if (t < nb) bsums[t] = tmp[t] - v;
}

__global__ __launch_bounds__(1024) void k_scan3(int* __restrict__ off,
                                                const int* __restrict__ bsums,
                                                int N, int E) {
    int i = blockIdx.x * 1024 + threadIdx.x;
    if (i < N) off[i] += bsums[blockIdx.x];
    if (i == 0) off[N] = E;
}

// ---------------- CSR fill ----------------
__global__ void k_fill(const int* __restrict__ src, const int* __restrict__ dst,
                       const int* __restrict__ off, int* __restrict__ cursor,
                       int* __restrict__ csr_src, int E) {
    int e = blockIdx.x * 256 + threadIdx.x;
    if (e < E) {
        int d = dst[e];
        int p = off[d] + atomicAdd(&cursor[d], 1);
        csr_src[p] = src[e];
    }
}

// ---------------- W prep: transpose + hi/lo bf16 split ----------------
__global__ void k_prepw(const float* __restrict__ W, bf16_t* __restrict__ Wh,
                        bf16_t* __restrict__ Wl, int K) {
    int id = blockIdx.x * 256 + threadIdx.x;   // id < K*128
    if (id >= K * 128) return;
    int k = id >> 7;
    int n = id & 127;
    float w = W[id];
    bf16_t h = (bf16_t)w;
    bf16_t l = (bf16_t)(w - (float)h);
    Wh[(size_t)n * K + k] = h;
    Wl[(size_t)n * K + k] = l;
}

// ---------------- MFMA GEMM: Cb[N,128] = bf16( dis[i] * (A[N,K] @ W[K,128]) )
// Compensated bf16: acc += Ah*Bh + Ah*Bl + Al*Bh.
// BM=64, BN=128(full), BK=32; 128 threads = 2 waves, each wave 64 rows x 64 cols.
// Grid = ceil(N/64) = 782 blocks -> ~3 blocks/CU (fixes grid starvation).
#define LDK 40
__global__ __launch_bounds__(128) void k_mm(const float* __restrict__ Af,
                                            const bf16_t* __restrict__ Ah,
                                            const bf16_t* __restrict__ Al,
                                            const bf16_t* __restrict__ Wh,
                                            const bf16_t* __restrict__ Wl,
                                            const float* __restrict__ dis,
                                            bf16_t* __restrict__ Cb,
                                            int N, int K, int a_fp32) {
    __shared__ bf16_t AsH[64][LDK];
    __shared__ bf16_t AsL[64][LDK];
    __shared__ bf16_t BsH[128][LDK];
    __shared__ bf16_t BsL[128][LDK];

    const int t    = threadIdx.x;
    const int lane = t & 63;
    const int wave = t >> 6;            // 0,1
    const int row0 = blockIdx.x * 64;
    const int wn   = wave * 64;         // wave's n offset (m shared)
    const int fm   = lane & 15;
    const int fq   = lane >> 4;

    f32x4 acc[4][4] = {};

    for (int k0 = 0; k0 < K; k0 += 32) {
        __syncthreads();
        if (a_fp32) {
            // 64 rows x 32 k fp32 = 512 float4; 4 per thread, split hi/lo
#pragma unroll
            for (int i = 0; i < 4; i++) {
                int idx = t + i * 128;      // 0..511
                int r   = idx >> 3;         // 8 float4 per row
                int c4  = idx & 7;
                int gr  = row0 + r;
                float4 v = make_float4(0.f, 0.f, 0.f, 0.f);
                if (gr < N) v = *(const float4*)(Af + (size_t)gr * K + k0 + c4 * 4);
                bf16_t h0 = (bf16_t)v.x, h1 = (bf16_t)v.y, h2 = (bf16_t)v.z, h3 = (bf16_t)v.w;
                bf16_t l0 = (bf16_t)(v.x - (float)h0);
                bf16_t l1 = (bf16_t)(v.y - (float)h1);
                bf16_t l2 = (bf16_t)(v.z - (float)h2);
                bf16_t l3 = (bf16_t)(v.w - (float)h3);
                *(bf16x4*)&AsH[r][c4 * 4] = (bf16x4){h0, h1, h2, h3};
                *(bf16x4*)&AsL[r][c4 * 4] = (bf16x4){l0, l1, l2, l3};
            }
        } else {
            // 64 rows x 32 k bf16: 256 bf16x8 per plane; 2 per thread per plane
#pragma unroll
            for (int i = 0; i < 2; i++) {
                int idx = t + i * 128;      // 0..255
                int r   = idx >> 2;
                int c8  = idx & 3;
                int gr  = row0 + r;
                bf16x8 vh = {}, vl = {};
                if (gr < N) {
                    vh = *(const bf16x8*)(Ah + (size_t)gr * K + k0 + c8 * 8);
                    vl = *(const bf16x8*)(Al + (size_t)gr * K + k0 + c8 * 8);
                }
                *(bf16x8*)&AsH[r][c8 * 8] = vh;
                *(bf16x8*)&AsL[r][c8 * 8] = vl;
            }
        }
        // stage B: 128 n x 32 k, 512 bf16x8 per plane; 4 per thread per plane
#pragma unroll
        for (int i = 0; i < 4; i++) {
            int idx = t + i * 128;
            int r   = idx >> 2;
            int c8  = idx & 3;
            *(bf16x8*)&BsH[r][c8 * 8] = *(const bf16x8*)(Wh + (size_t)r * K + k0 + c8 * 8);
            *(bf16x8*)&BsL[r][c8 * 8] = *(const bf16x8*)(Wl + (size_t)r * K + k0 + c8 * 8);
        }
        __syncthreads();

        bf16x8 ah[4], al[4], bh[4], bl[4];
#pragma unroll
        for (int i = 0; i < 4; i++) {
            ah[i] = *(const bf16x8*)&AsH[i * 16 + fm][fq * 8];
            al[i] = *(const bf16x8*)&AsL[i * 16 + fm][fq * 8];
            bh[i] = *(const bf16x8*)&BsH[wn + i * 16 + fm][fq * 8];
            bl[i] = *(const bf16x8*)&BsL[wn + i * 16 + fm][fq * 8];
        }
#pragma unroll
        for (int mi = 0; mi < 4; mi++)
#pragma unroll
            for (int ni = 0; ni < 4; ni++) {
                acc[mi][ni] = __builtin_amdgcn_mfma_f32_16x16x32_bf16(ah[mi], bh[ni], acc[mi][ni], 0, 0, 0);
                acc[mi][ni] = __builtin_amdgcn_mfma_f32_16x16x32_bf16(ah[mi], bl[ni], acc[mi][ni], 0, 0, 0);
                acc[mi][ni] = __builtin_amdgcn_mfma_f32_16x16x32_bf16(al[mi], bh[ni], acc[mi][ni], 0, 0, 0);
            }
    }

    // epilogue: C/D layout col=fm, row=fq*4+reg; scale by dis[row], store bf16
#pragma unroll
    for (int mi = 0; mi < 4; mi++)
#pragma unroll
        for (int r = 0; r < 4; r++) {
            int grow = row0 + mi * 16 + fq * 4 + r;
            if (grow < N) {
                float dr = dis[grow];
#pragma unroll
                for (int ni = 0; ni < 4; ni++)
                    Cb[(size_t)grow * D_H + wn + ni * 16 + fm] = (bf16_t)(dr * acc[mi][ni][r]);
            }
        }
}

// ---------------- aggregation ----------------
// Input Hb = bf16 dis-scaled rows H'. out[i] = (relu?)(b + di*(H'[i] + sum_s H'[s]))
// 32 lanes per node (bf16x4/lane = 8B, row = 256B), 8 nodes per 256-block.
// Edge loop unrolled x8 with 8 independent fp32 accumulators.
__global__ __launch_bounds__(256) void k_agg(const bf16_t* __restrict__ Hb,
                                             const float* __restrict__ dis,
                                             const int* __restrict__ off,
                                             const int* __restrict__ csr_src,
                                             const float4* __restrict__ bias4,
                                             float4* __restrict__ outF,
                                             bf16_t* __restrict__ outH,
                                             bf16_t* __restrict__ outL,
                                             int N, int mode) {
    const int half = threadIdx.x >> 5;           // 0..7: node slot in block
    const int lane = threadIdx.x & 31;           // feature group (4 bf16)
    const int node = blockIdx.x * 8 + half;
    if (node >= N) return;

    const size_t loff = (size_t)lane * 4;

    bf16x4 vs = *(const bf16x4*)(Hb + (size_t)node * D_H + loff);
    float4 a0 = make_float4((float)vs[0], (float)vs[1], (float)vs[2], (float)vs[3]);
    float4 a1 = {0,0,0,0}, a2 = {0,0,0,0}, a3 = {0,0,0,0};
    float4 a4 = {0,0,0,0}, a5 = {0,0,0,0}, a6 = {0,0,0,0}, a7 = {0,0,0,0};

    int p  = off[node];
    int p1 = off[node + 1];

    for (; p + 8 <= p1; p += 8) {
        int s0 = csr_src[p + 0], s1 = csr_src[p + 1];
        int s2 = csr_src[p + 2], s3 = csr_src[p + 3];
        int s4 = csr_src[p + 4], s5 = csr_src[p + 5];
        int s6 = csr_src[p + 6], s7 = csr_src[p + 7];
        bf16x4 h0 = *(const bf16x4*)(Hb + (size_t)s0 * D_H + loff);
        bf16x4 h1 = *(const bf16x4*)(Hb + (size_t)s1 * D_H + loff);
        bf16x4 h2 = *(const bf16x4*)(Hb + (size_t)s2 * D_H + loff);
        bf16x4 h3 = *(const bf16x4*)(Hb + (size_t)s3 * D_H + loff);
        bf16x4 h4 = *(const bf16x4*)(Hb + (size_t)s4 * D_H + loff);
        bf16x4 h5 = *(const bf16x4*)(Hb + (size_t)s5 * D_H + loff);
        bf16x4 h6 = *(const bf16x4*)(Hb + (size_t)s6 * D_H + loff);
        bf16x4 h7 = *(const bf16x4*)(Hb + (size_t)s7 * D_H + loff);
        a0.x += (float)h0[0]; a0.y += (float)h0[1]; a0.z += (float)h0[2]; a0.w += (float)h0[3];
        a1.x += (float)h1[0]; a1.y += (float)h1[1]; a1.z += (float)h1[2]; a1.w += (float)h1[3];
        a2.x += (float)h2[0]; a2.y += (float)h2[1]; a2.z += (float)h2[2]; a2.w += (float)h2[3];
        a3.x += (float)h3[0]; a3.y += (float)h3[1]; a3.z += (float)h3[2]; a3.w += (float)h3[3];
        a4.x += (float)h4[0]; a4.y += (float)h4[1]; a4.z += (float)h4[2]; a4.w += (float)h4[3];
        a5.x += (float)h5[0]; a5.y += (float)h5[1]; a5.z += (float)h5[2]; a5.w += (float)h5[3];
        a6.x += (float)h6[0]; a6.y += (float)h6[1]; a6.z += (float)h6[2]; a6.w += (float)h6[3];
        a7.x += (float)h7[0]; a7.y += (float)h7[1]; a7.z += (float)h7[2]; a7.w += (float)h7[3];
    }
    if (p + 4 <= p1) {
        int s0 = csr_src[p + 0], s1 = csr_src[p + 1];
        int s2 = csr_src[p + 2], s3 = csr_src[p + 3];
        bf16x4 h0 = *(const bf16x4*)(Hb + (size_t)s0 * D_H + loff);
        bf16x4 h1 = *(const bf16x4*)(Hb + (size_t)s1 * D_H + loff);
        bf16x4 h2 = *(const bf16x4*)(Hb + (size_t)s2 * D_H + loff);
        bf16x4 h3 = *(const bf16x4*)(Hb + (size_t)s3 * D_H + loff);
        a0.x += (float)h0[0]; a0.y += (float)h0[1]; a0.z += (float)h0[2]; a0.w += (float)h0[3];
        a1.x += (float)h1[0]; a1.y += (float)h1[1]; a1.z += (float)h1[2]; a1.w += (float)h1[3];
        a2.x += (float)h2[0]; a2.y += (float)h2[1]; a2.z += (float)h2[2]; a2.w += (float)h2[3];
        a3.x += (float)h3[0]; a3.y += (float)h3[1]; a3.z += (float)h3[2]; a3.w += (float)h3[3];
        p += 4;
    }
    for (; p < p1; p++) {
        int s0 = csr_src[p];
        bf16x4 h0 = *(const bf16x4*)(Hb + (size_t)s0 * D_H + loff);
        a0.x += (float)h0[0]; a0.y += (float)h0[1]; a0.z += (float)h0[2]; a0.w += (float)h0[3];
    }

    float4 sum;
    sum.x = ((a0.x + a1.x) + (a2.x + a3.x)) + ((a4.x + a5.x) + (a6.x + a7.x));
    sum.y = ((a0.y + a1.y) + (a2.y + a3.y)) + ((a4.y + a5.y) + (a6.y + a7.y));
    sum.z = ((a0.z + a1.z) + (a2.z + a3.z)) + ((a4.z + a5.z) + (a6.z + a7.z));
    sum.w = ((a0.w + a1.w) + (a2.w + a3.w)) + ((a4.w + a5.w) + (a6.w + a7.w));

    const float  di = dis[node];
    const float4 bv = bias4[lane];
    float vx = fmaf(di, sum.x, bv.x);
    float vy = fmaf(di, sum.y, bv.y);
    float vz = fmaf(di, sum.z, bv.z);
    float vw = fmaf(di, sum.w, bv.w);

    if (mode == 1) {
        vx = fmaxf(vx, 0.0f); vy = fmaxf(vy, 0.0f);
        vz = fmaxf(vz, 0.0f); vw = fmaxf(vw, 0.0f);
        bf16_t hx = (bf16_t)vx, hy = (bf16_t)vy, hz = (bf16_t)vz, hw = (bf16_t)vw;
        bf16_t lx = (bf16_t)(vx - (float)hx);
        bf16_t ly = (bf16_t)(vy - (float)hy);
        bf16_t lz = (bf16_t)(vz - (float)hz);
        bf16_t lw = (bf16_t)(vw - (float)hw);
        *(bf16x4*)(outH + (size_t)node * D_H + loff) = (bf16x4){hx, hy, hz, hw};
        *(bf16x4*)(outL + (size_t)node * D_H + loff) = (bf16x4){lx, ly, lz, lw};
    } else {
        outF[(size_t)node * 32 + lane] = make_float4(vx, vy, vz, vw);
    }
}

extern "C" void kernel_launch(void* const* d_in, const int* in_sizes, int n_in,
                              void* d_out, int out_size, void* d_ws, size_t ws_size,
                              hipStream_t stream) {
    const float* X  = (const float*)d_in[0];
    const int*   ei = (const int*)d_in[1];
    const float* W1 = (const float*)d_in[2];
    const float* b1 = (const float*)d_in[3];
    const float* W2 = (const float*)d_in[4];
    const float* b2 = (const float*)d_in[5];
    float* out = (float*)d_out;

    const int N  = in_sizes[0] / 256;   // 50000
    const int E  = in_sizes[1] / 2;     // 800000
    const int K1 = 256;

    const int* src = ei;
    const int* dst = ei + E;

    uintptr_t p = (uintptr_t)d_ws;
    auto carve = [&](size_t bytes) {
        uintptr_t q = p;
        p += (bytes + 255) & ~(size_t)255;
        return q;
    };
    int*    cnt   = (int*)carve((size_t)N * 4);
    int*    off   = (int*)carve((size_t)(N + 1) * 4);
    int*    bsums = (int*)carve(64 * 4);
    float*  dis   = (float*)carve((size_t)N * 4);
    int*    csr   = (int*)carve((size_t)E * 4);
    bf16_t* Hb    = (bf16_t*)carve((size_t)N * D_H * 2);   // bf16 dis-scaled H'
    bf16_t* X1h   = (bf16_t*)carve((size_t)N * D_H * 2);
    bf16_t* X1l   = (bf16_t*)carve((size_t)N * D_H * 2);
    bf16_t* W1h   = (bf16_t*)carve((size_t)K1 * D_H * 2);
    bf16_t* W1l   = (bf16_t*)carve((size_t)K1 * D_H * 2);
    bf16_t* W2h   = (bf16_t*)carve((size_t)D_H * D_H * 2);
    bf16_t* W2l   = (bf16_t*)carve((size_t)D_H * D_H * 2);

    const int nb = (N + 1023) / 1024;

    // weight prep (tiny)
    k_prepw<<<(K1 * 128 + 255) / 256, 256, 0, stream>>>(W1, W1h, W1l, K1);
    k_prepw<<<(D_H * 128 + 255) / 256, 256, 0, stream>>>(W2, W2h, W2l, D_H);

    // graph preprocessing
    hipMemsetAsync(cnt, 0, (size_t)N * 4, stream);
    k_count<<<(E + 255) / 256, 256, 0, stream>>>(dst, cnt, E);
    k_dis<<<(N + 255) / 256, 256, 0, stream>>>(cnt, dis, N);
    k_scan1<<<nb, 1024, 0, stream>>>(cnt, off, bsums, N);
    k_scan2<<<1, 64, 0, stream>>>(bsums, nb);
    k_scan3<<<nb, 1024, 0, stream>>>(off, bsums, N, E);
    hipMemsetAsync(cnt, 0, (size_t)N * 4, stream);
    k_fill<<<(E + 255) / 256, 256, 0, stream>>>(src, dst, off, cnt, csr, E);

    const int gmm = (N + 63) / 64;
    const int gag = (N + 7) / 8;

    // layer 1: Hb = bf16(dis .* (X @ W1)); X1 = relu(agg(Hb)+b1) -> hi/lo bf16
    k_mm<<<gmm, 128, 0, stream>>>(X, nullptr, nullptr, W1h, W1l, dis, Hb, N, K1, 1);
    k_agg<<<gag, 256, 0, stream>>>(Hb, dis, off, csr,
                                   (const float4*)b1, nullptr, X1h, X1l, N, 1);

    // layer 2: Hb = bf16(dis .* (X1 @ W2)); out = agg(Hb) + b2
    k_mm<<<gmm, 128, 0, stream>>>(nullptr, X1h, X1l, W2h, W2l, dis, Hb, N, D_H, 0);
    k_agg<<<gag, 256, 0, stream>>>(Hb, dis, off, csr,
                                   (const float4*)b2, (float4*)out, nullptr, nullptr, N, 0);
}

// Round 6
// 271.049 us; speedup vs baseline: 2.0724x; 1.1373x over previous
//
#include <hip/hip_runtime.h>
#include <hip/hip_bf16.h>
#include <stdint.h>

#define D_H 128

typedef __bf16 bf16_t;
typedef unsigned short u16;
typedef bf16_t bf16x8 __attribute__((ext_vector_type(8)));
typedef bf16_t bf16x4 __attribute__((ext_vector_type(4)));
typedef float  f32x4  __attribute__((ext_vector_type(4)));

// ---------------- degree count + rank capture ----------------
// rank[e] = position of edge e within its dst bucket (any permutation is valid)
__global__ void k_countrank(const int* __restrict__ dst, int* __restrict__ cnt,
                            u16* __restrict__ rank, int E) {
    int e = blockIdx.x * 256 + threadIdx.x;
    if (e < E) rank[e] = (u16)atomicAdd(&cnt[dst[e]], 1);
}

// ---------------- exclusive scan (3 kernels); scan1 also emits dis ----------
__global__ __launch_bounds__(1024) void k_scan1(const int* __restrict__ cnt,
                                                int* __restrict__ out,
                                                int* __restrict__ bsums,
                                                float* __restrict__ dis, int N) {
    __shared__ int tmp[1024];
    int t = threadIdx.x;
    int i = blockIdx.x * 1024 + t;
    int v = (i < N) ? cnt[i] : 0;
    if (i < N) dis[i] = 1.0f / sqrtf((float)(v + 1));   // self-loop included
    tmp[t] = v;
    __syncthreads();
    for (int d = 1; d < 1024; d <<= 1) {
        int x = (t >= d) ? tmp[t - d] : 0;
        __syncthreads();
        tmp[t] += x;
        __syncthreads();
    }
    if (i < N) out[i] = tmp[t] - v;
    if (t == 1023) bsums[blockIdx.x] = tmp[t];
}

__global__ void k_scan2(int* __restrict__ bsums, int nb) {
    __shared__ int tmp[64];
    int t = threadIdx.x;
    int v = (t < nb) ? bsums[t] : 0;
    tmp[t] = v;
    __syncthreads();
    for (int d = 1; d < 64; d <<= 1) {
        int x = (t >= d) ? tmp[t - d] : 0;
        __syncthreads();
        tmp[t] += x;
        __syncthreads();
    }
    if (t < nb) bsums[t] = tmp[t] - v;
}

__global__ __launch_bounds__(1024) void k_scan3(int* __restrict__ off,
                                                const int* __restrict__ bsums,
                                                int N, int E) {
    int i = blockIdx.x * 1024 + threadIdx.x;
    if (i < N) off[i] += bsums[blockIdx.x];
    if (i == 0) off[N] = E;
}

// ---------------- W prep: transpose + hi/lo bf16 split ----------------
__global__ void k_prepw(const float* __restrict__ W, bf16_t* __restrict__ Wh,
                        bf16_t* __restrict__ Wl, int K) {
    int id = blockIdx.x * 256 + threadIdx.x;   // id < K*128
    if (id >= K * 128) return;
    int k = id >> 7;
    int n = id & 127;
    float w = W[id];
    bf16_t h = (bf16_t)w;
    bf16_t l = (bf16_t)(w - (float)h);
    Wh[(size_t)n * K + k] = h;
    Wl[(size_t)n * K + k] = l;
}

// ---------------- fused: layer-1 MFMA GEMM (fp32 A) + atomic-free CSR fill --
// blocks [0,mmBlocks): Cb[N,128] = bf16(dis[i] * (Af[N,K] @ W[K,128]))
// blocks [mmBlocks,..): csr16[off[dst[e]] + rank[e]] = (u16)src[e]
#define LDK 40
__global__ __launch_bounds__(128) void k_mm1fill(
        const float* __restrict__ Af,
        const bf16_t* __restrict__ Wh, const bf16_t* __restrict__ Wl,
        const float* __restrict__ dis, bf16_t* __restrict__ Cb,
        int N, int K, int mmBlocks,
        const int* __restrict__ src, const int* __restrict__ dst,
        const int* __restrict__ off, const u16* __restrict__ rank,
        u16* __restrict__ csr16, int E) {
    __shared__ bf16_t AsH[64][LDK];
    __shared__ bf16_t AsL[64][LDK];
    __shared__ bf16_t BsH[128][LDK];
    __shared__ bf16_t BsL[128][LDK];

    if ((int)blockIdx.x >= mmBlocks) {
        int e = ((int)blockIdx.x - mmBlocks) * 128 + threadIdx.x;
        if (e < E) {
            int d = dst[e];
            csr16[off[d] + (int)rank[e]] = (u16)src[e];
        }
        return;
    }

    const int t    = threadIdx.x;
    const int lane = t & 63;
    const int wave = t >> 6;            // 0,1
    const int row0 = blockIdx.x * 64;
    const int wn   = wave * 64;
    const int fm   = lane & 15;
    const int fq   = lane >> 4;

    f32x4 acc[4][4] = {};

    for (int k0 = 0; k0 < K; k0 += 32) {
        __syncthreads();
        // stage A: 64 rows x 32 k fp32 = 512 float4; split hi/lo
#pragma unroll
        for (int i = 0; i < 4; i++) {
            int idx = t + i * 128;
            int r   = idx >> 3;
            int c4  = idx & 7;
            int gr  = row0 + r;
            float4 v = make_float4(0.f, 0.f, 0.f, 0.f);
            if (gr < N) v = *(const float4*)(Af + (size_t)gr * K + k0 + c4 * 4);
            bf16_t h0 = (bf16_t)v.x, h1 = (bf16_t)v.y, h2 = (bf16_t)v.z, h3 = (bf16_t)v.w;
            bf16_t l0 = (bf16_t)(v.x - (float)h0);
            bf16_t l1 = (bf16_t)(v.y - (float)h1);
            bf16_t l2 = (bf16_t)(v.z - (float)h2);
            bf16_t l3 = (bf16_t)(v.w - (float)h3);
            *(bf16x4*)&AsH[r][c4 * 4] = (bf16x4){h0, h1, h2, h3};
            *(bf16x4*)&AsL[r][c4 * 4] = (bf16x4){l0, l1, l2, l3};
        }
        // stage B: 128 n x 32 k
#pragma unroll
        for (int i = 0; i < 4; i++) {
            int idx = t + i * 128;
            int r   = idx >> 2;
            int c8  = idx & 3;
            *(bf16x8*)&BsH[r][c8 * 8] = *(const bf16x8*)(Wh + (size_t)r * K + k0 + c8 * 8);
            *(bf16x8*)&BsL[r][c8 * 8] = *(const bf16x8*)(Wl + (size_t)r * K + k0 + c8 * 8);
        }
        __syncthreads();

        bf16x8 ah[4], al[4], bh[4], bl[4];
#pragma unroll
        for (int i = 0; i < 4; i++) {
            ah[i] = *(const bf16x8*)&AsH[i * 16 + fm][fq * 8];
            al[i] = *(const bf16x8*)&AsL[i * 16 + fm][fq * 8];
            bh[i] = *(const bf16x8*)&BsH[wn + i * 16 + fm][fq * 8];
            bl[i] = *(const bf16x8*)&BsL[wn + i * 16 + fm][fq * 8];
        }
#pragma unroll
        for (int mi = 0; mi < 4; mi++)
#pragma unroll
            for (int ni = 0; ni < 4; ni++) {
                acc[mi][ni] = __builtin_amdgcn_mfma_f32_16x16x32_bf16(ah[mi], bh[ni], acc[mi][ni], 0, 0, 0);
                acc[mi][ni] = __builtin_amdgcn_mfma_f32_16x16x32_bf16(ah[mi], bl[ni], acc[mi][ni], 0, 0, 0);
                acc[mi][ni] = __builtin_amdgcn_mfma_f32_16x16x32_bf16(al[mi], bh[ni], acc[mi][ni], 0, 0, 0);
            }
    }

#pragma unroll
    for (int mi = 0; mi < 4; mi++)
#pragma unroll
        for (int r = 0; r < 4; r++) {
            int grow = row0 + mi * 16 + fq * 4 + r;
            if (grow < N) {
                float dr = dis[grow];
#pragma unroll
                for (int ni = 0; ni < 4; ni++)
                    Cb[(size_t)grow * D_H + wn + ni * 16 + fm] = (bf16_t)(dr * acc[mi][ni][r]);
            }
        }
}

// ---------------- layer-2 MFMA GEMM (bf16 hi/lo A) ----------------
__global__ __launch_bounds__(128) void k_mm2(const bf16_t* __restrict__ Ah,
                                             const bf16_t* __restrict__ Al,
                                             const bf16_t* __restrict__ Wh,
                                             const bf16_t* __restrict__ Wl,
                                             const float* __restrict__ dis,
                                             bf16_t* __restrict__ Cb,
                                             int N, int K) {
    __shared__ bf16_t AsH[64][LDK];
    __shared__ bf16_t AsL[64][LDK];
    __shared__ bf16_t BsH[128][LDK];
    __shared__ bf16_t BsL[128][LDK];

    const int t    = threadIdx.x;
    const int lane = t & 63;
    const int wave = t >> 6;
    const int row0 = blockIdx.x * 64;
    const int wn   = wave * 64;
    const int fm   = lane & 15;
    const int fq   = lane >> 4;

    f32x4 acc[4][4] = {};

    for (int k0 = 0; k0 < K; k0 += 32) {
        __syncthreads();
#pragma unroll
        for (int i = 0; i < 2; i++) {
            int idx = t + i * 128;
            int r   = idx >> 2;
            int c8  = idx & 3;
            int gr  = row0 + r;
            bf16x8 vh = {}, vl = {};
            if (gr < N) {
                vh = *(const bf16x8*)(Ah + (size_t)gr * K + k0 + c8 * 8);
                vl = *(const bf16x8*)(Al + (size_t)gr * K + k0 + c8 * 8);
            }
            *(bf16x8*)&AsH[r][c8 * 8] = vh;
            *(bf16x8*)&AsL[r][c8 * 8] = vl;
        }
#pragma unroll
        for (int i = 0; i < 4; i++) {
            int idx = t + i * 128;
            int r   = idx >> 2;
            int c8  = idx & 3;
            *(bf16x8*)&BsH[r][c8 * 8] = *(const bf16x8*)(Wh + (size_t)r * K + k0 + c8 * 8);
            *(bf16x8*)&BsL[r][c8 * 8] = *(const bf16x8*)(Wl + (size_t)r * K + k0 + c8 * 8);
        }
        __syncthreads();

        bf16x8 ah[4], al[4], bh[4], bl[4];
#pragma unroll
        for (int i = 0; i < 4; i++) {
            ah[i] = *(const bf16x8*)&AsH[i * 16 + fm][fq * 8];
            al[i] = *(const bf16x8*)&AsL[i * 16 + fm][fq * 8];
            bh[i] = *(const bf16x8*)&BsH[wn + i * 16 + fm][fq * 8];
            bl[i] = *(const bf16x8*)&BsL[wn + i * 16 + fm][fq * 8];
        }
#pragma unroll
        for (int mi = 0; mi < 4; mi++)
#pragma unroll
            for (int ni = 0; ni < 4; ni++) {
                acc[mi][ni] = __builtin_amdgcn_mfma_f32_16x16x32_bf16(ah[mi], bh[ni], acc[mi][ni], 0, 0, 0);
                acc[mi][ni] = __builtin_amdgcn_mfma_f32_16x16x32_bf16(ah[mi], bl[ni], acc[mi][ni], 0, 0, 0);
                acc[mi][ni] = __builtin_amdgcn_mfma_f32_16x16x32_bf16(al[mi], bh[ni], acc[mi][ni], 0, 0, 0);
            }
    }

#pragma unroll
    for (int mi = 0; mi < 4; mi++)
#pragma unroll
        for (int r = 0; r < 4; r++) {
            int grow = row0 + mi * 16 + fq * 4 + r;
            if (grow < N) {
                float dr = dis[grow];
#pragma unroll
                for (int ni = 0; ni < 4; ni++)
                    Cb[(size_t)grow * D_H + wn + ni * 16 + fm] = (bf16_t)(dr * acc[mi][ni][r]);
            }
        }
}

// ---------------- aggregation ----------------
// Input Hb = bf16 dis-scaled rows H'. out[i] = (relu?)(b + di*(H'[i] + sum_s H'[s]))
// 32 lanes per node (bf16x4/lane = 8B, row = 256B), 8 nodes per 256-block.
__global__ __launch_bounds__(256) void k_agg(const bf16_t* __restrict__ Hb,
                                             const float* __restrict__ dis,
                                             const int* __restrict__ off,
                                             const u16* __restrict__ csr16,
                                             const float4* __restrict__ bias4,
                                             float4* __restrict__ outF,
                                             bf16_t* __restrict__ outH,
                                             bf16_t* __restrict__ outL,
                                             int N, int mode) {
    const int half = threadIdx.x >> 5;
    const int lane = threadIdx.x & 31;
    const int node = blockIdx.x * 8 + half;
    if (node >= N) return;

    const size_t loff = (size_t)lane * 4;

    bf16x4 vs = *(const bf16x4*)(Hb + (size_t)node * D_H + loff);
    float4 a0 = make_float4((float)vs[0], (float)vs[1], (float)vs[2], (float)vs[3]);
    float4 a1 = {0,0,0,0}, a2 = {0,0,0,0}, a3 = {0,0,0,0};
    float4 a4 = {0,0,0,0}, a5 = {0,0,0,0}, a6 = {0,0,0,0}, a7 = {0,0,0,0};

    int p  = off[node];
    int p1 = off[node + 1];

    for (; p + 8 <= p1; p += 8) {
        int s0 = (int)csr16[p + 0], s1 = (int)csr16[p + 1];
        int s2 = (int)csr16[p + 2], s3 = (int)csr16[p + 3];
        int s4 = (int)csr16[p + 4], s5 = (int)csr16[p + 5];
        int s6 = (int)csr16[p + 6], s7 = (int)csr16[p + 7];
        bf16x4 h0 = *(const bf16x4*)(Hb + (size_t)s0 * D_H + loff);
        bf16x4 h1 = *(const bf16x4*)(Hb + (size_t)s1 * D_H + loff);
        bf16x4 h2 = *(const bf16x4*)(Hb + (size_t)s2 * D_H + loff);
        bf16x4 h3 = *(const bf16x4*)(Hb + (size_t)s3 * D_H + loff);
        bf16x4 h4 = *(const bf16x4*)(Hb + (size_t)s4 * D_H + loff);
        bf16x4 h5 = *(const bf16x4*)(Hb + (size_t)s5 * D_H + loff);
        bf16x4 h6 = *(const bf16x4*)(Hb + (size_t)s6 * D_H + loff);
        bf16x4 h7 = *(const bf16x4*)(Hb + (size_t)s7 * D_H + loff);
        a0.x += (float)h0[0]; a0.y += (float)h0[1]; a0.z += (float)h0[2]; a0.w += (float)h0[3];
        a1.x += (float)h1[0]; a1.y += (float)h1[1]; a1.z += (float)h1[2]; a1.w += (float)h1[3];
        a2.x += (float)h2[0]; a2.y += (float)h2[1]; a2.z += (float)h2[2]; a2.w += (float)h2[3];
        a3.x += (float)h3[0]; a3.y += (float)h3[1]; a3.z += (float)h3[2]; a3.w += (float)h3[3];
        a4.x += (float)h4[0]; a4.y += (float)h4[1]; a4.z += (float)h4[2]; a4.w += (float)h4[3];
        a5.x += (float)h5[0]; a5.y += (float)h5[1]; a5.z += (float)h5[2]; a5.w += (float)h5[3];
        a6.x += (float)h6[0]; a6.y += (float)h6[1]; a6.z += (float)h6[2]; a6.w += (float)h6[3];
        a7.x += (float)h7[0]; a7.y += (float)h7[1]; a7.z += (float)h7[2]; a7.w += (float)h7[3];
    }
    if (p + 4 <= p1) {
        int s0 = (int)csr16[p + 0], s1 = (int)csr16[p + 1];
        int s2 = (int)csr16[p + 2], s3 = (int)csr16[p + 3];
        bf16x4 h0 = *(const bf16x4*)(Hb + (size_t)s0 * D_H + loff);
        bf16x4 h1 = *(const bf16x4*)(Hb + (size_t)s1 * D_H + loff);
        bf16x4 h2 = *(const bf16x4*)(Hb + (size_t)s2 * D_H + loff);
        bf16x4 h3 = *(const bf16x4*)(Hb + (size_t)s3 * D_H + loff);
        a0.x += (float)h0[0]; a0.y += (float)h0[1]; a0.z += (float)h0[2]; a0.w += (float)h0[3];
        a1.x += (float)h1[0]; a1.y += (float)h1[1]; a1.z += (float)h1[2]; a1.w += (float)h1[3];
        a2.x += (float)h2[0]; a2.y += (float)h2[1]; a2.z += (float)h2[2]; a2.w += (float)h2[3];
        a3.x += (float)h3[0]; a3.y += (float)h3[1]; a3.z += (float)h3[2]; a3.w += (float)h3[3];
        p += 4;
    }
    for (; p < p1; p++) {
        int s0 = (int)csr16[p];
        bf16x4 h0 = *(const bf16x4*)(Hb + (size_t)s0 * D_H + loff);
        a0.x += (float)h0[0]; a0.y += (float)h0[1]; a0.z += (float)h0[2]; a0.w += (float)h0[3];
    }

    float4 sum;
    sum.x = ((a0.x + a1.x) + (a2.x + a3.x)) + ((a4.x + a5.x) + (a6.x + a7.x));
    sum.y = ((a0.y + a1.y) + (a2.y + a3.y)) + ((a4.y + a5.y) + (a6.y + a7.y));
    sum.z = ((a0.z + a1.z) + (a2.z + a3.z)) + ((a4.z + a5.z) + (a6.z + a7.z));
    sum.w = ((a0.w + a1.w) + (a2.w + a3.w)) + ((a4.w + a5.w) + (a6.w + a7.w));

    const float  di = dis[node];
    const float4 bv = bias4[lane];
    float vx = fmaf(di, sum.x, bv.x);
    float vy = fmaf(di, sum.y, bv.y);
    float vz = fmaf(di, sum.z, bv.z);
    float vw = fmaf(di, sum.w, bv.w);

    if (mode == 1) {
        vx = fmaxf(vx, 0.0f); vy = fmaxf(vy, 0.0f);
        vz = fmaxf(vz, 0.0f); vw = fmaxf(vw, 0.0f);
        bf16_t hx = (bf16_t)vx, hy = (bf16_t)vy, hz = (bf16_t)vz, hw = (bf16_t)vw;
        bf16_t lx = (bf16_t)(vx - (float)hx);
        bf16_t ly = (bf16_t)(vy - (float)hy);
        bf16_t lz = (bf16_t)(vz - (float)hz);
        bf16_t lw = (bf16_t)(vw - (float)hw);
        *(bf16x4*)(outH + (size_t)node * D_H + loff) = (bf16x4){hx, hy, hz, hw};
        *(bf16x4*)(outL + (size_t)node * D_H + loff) = (bf16x4){lx, ly, lz, lw};
    } else {
        outF[(size_t)node * 32 + lane] = make_float4(vx, vy, vz, vw);
    }
}

extern "C" void kernel_launch(void* const* d_in, const int* in_sizes, int n_in,
                              void* d_out, int out_size, void* d_ws, size_t ws_size,
                              hipStream_t stream) {
    const float* X  = (const float*)d_in[0];
    const int*   ei = (const int*)d_in[1];
    const float* W1 = (const float*)d_in[2];
    const float* b1 = (const float*)d_in[3];
    const float* W2 = (const float*)d_in[4];
    const float* b2 = (const float*)d_in[5];
    float* out = (float*)d_out;

    const int N  = in_sizes[0] / 256;   // 50000
    const int E  = in_sizes[1] / 2;     // 800000
    const int K1 = 256;

    const int* src = ei;
    const int* dst = ei + E;

    uintptr_t p = (uintptr_t)d_ws;
    auto carve = [&](size_t bytes) {
        uintptr_t q = p;
        p += (bytes + 255) & ~(size_t)255;
        return q;
    };
    int*    cnt   = (int*)carve((size_t)N * 4);
    int*    off   = (int*)carve((size_t)(N + 1) * 4);
    int*    bsums = (int*)carve(64 * 4);
    float*  dis   = (float*)carve((size_t)N * 4);
    u16*    rank  = (u16*)carve((size_t)E * 2);
    u16*    csr16 = (u16*)carve((size_t)E * 2);
    bf16_t* Hb    = (bf16_t*)carve((size_t)N * D_H * 2);
    bf16_t* X1h   = (bf16_t*)carve((size_t)N * D_H * 2);
    bf16_t* X1l   = (bf16_t*)carve((size_t)N * D_H * 2);
    bf16_t* W1h   = (bf16_t*)carve((size_t)K1 * D_H * 2);
    bf16_t* W1l   = (bf16_t*)carve((size_t)K1 * D_H * 2);
    bf16_t* W2h   = (bf16_t*)carve((size_t)D_H * D_H * 2);
    bf16_t* W2l   = (bf16_t*)carve((size_t)D_H * D_H * 2);

    const int nb = (N + 1023) / 1024;

    // weight prep (tiny)
    k_prepw<<<(K1 * 128 + 255) / 256, 256, 0, stream>>>(W1, W1h, W1l, K1);
    k_prepw<<<(D_H * 128 + 255) / 256, 256, 0, stream>>>(W2, W2h, W2l, D_H);

    // graph preprocessing
    hipMemsetAsync(cnt, 0, (size_t)N * 4, stream);
    k_countrank<<<(E + 255) / 256, 256, 0, stream>>>(dst, cnt, rank, E);
    k_scan1<<<nb, 1024, 0, stream>>>(cnt, off, bsums, dis, N);
    k_scan2<<<1, 64, 0, stream>>>(bsums, nb);
    k_scan3<<<nb, 1024, 0, stream>>>(off, bsums, N, E);

    const int gmm  = (N + 63) / 64;          // 782 GEMM blocks
    const int gfil = (E + 127) / 128;        // 6250 fill blocks
    const int gag  = (N + 7) / 8;

    // layer 1 GEMM + CSR fill fused (independent work, overlapped)
    k_mm1fill<<<gmm + gfil, 128, 0, stream>>>(X, W1h, W1l, dis, Hb, N, K1, gmm,
                                              src, dst, off, rank, csr16, E);
    k_agg<<<gag, 256, 0, stream>>>(Hb, dis, off, csr16,
                                   (const float4*)b1, nullptr, X1h, X1l, N, 1);

    // layer 2
    k_mm2<<<gmm, 128, 0, stream>>>(X1h, X1l, W2h, W2l, dis, Hb, N, D_H);
    k_agg<<<gag, 256, 0, stream>>>(Hb, dis, off, csr16,
                                   (const float4*)b2, (float4*)out, nullptr, nullptr, N, 0);
}

// Round 7
// 265.360 us; speedup vs baseline: 2.1168x; 1.0214x over previous
//
#include <hip/hip_runtime.h>
#include <hip/hip_bf16.h>
#include <stdint.h>

#define D_H 128

typedef __bf16 bf16_t;
typedef unsigned short u16;
typedef bf16_t bf16x8 __attribute__((ext_vector_type(8)));
typedef bf16_t bf16x4 __attribute__((ext_vector_type(4)));
typedef float  f32x4  __attribute__((ext_vector_type(4)));

// ---------------- degree count + rank capture + weight prep (fused) --------
// blocks [0, crBlocks): rank[e] = atomicAdd(&cnt[dst[e]], 1)
// blocks [crBlocks, ..): transpose + hi/lo split of W1 then W2
__global__ void k_countrank(const int* __restrict__ dst, int* __restrict__ cnt,
                            u16* __restrict__ rank, int E, int crBlocks,
                            const float* __restrict__ W1, bf16_t* __restrict__ W1h,
                            bf16_t* __restrict__ W1l, int K1,
                            const float* __restrict__ W2, bf16_t* __restrict__ W2h,
                            bf16_t* __restrict__ W2l, int K2) {
    if ((int)blockIdx.x < crBlocks) {
        int e = blockIdx.x * 256 + threadIdx.x;
        if (e < E) rank[e] = (u16)atomicAdd(&cnt[dst[e]], 1);
        return;
    }
    int id = ((int)blockIdx.x - crBlocks) * 256 + threadIdx.x;
    int n1 = K1 * 128;
    if (id < n1) {
        int k = id >> 7, n = id & 127;
        float w = W1[id];
        bf16_t h = (bf16_t)w;
        W1h[(size_t)n * K1 + k] = h;
        W1l[(size_t)n * K1 + k] = (bf16_t)(w - (float)h);
    } else if (id < n1 + K2 * 128) {
        int id2 = id - n1;
        int k = id2 >> 7, n = id2 & 127;
        float w = W2[id2];
        bf16_t h = (bf16_t)w;
        W2h[(size_t)n * K2 + k] = h;
        W2l[(size_t)n * K2 + k] = (bf16_t)(w - (float)h);
    }
}

// ---------------- exclusive scan (3 kernels); scan1 also emits dis ----------
__global__ __launch_bounds__(1024) void k_scan1(const int* __restrict__ cnt,
                                                int* __restrict__ out,
                                                int* __restrict__ bsums,
                                                float* __restrict__ dis, int N) {
    __shared__ int tmp[1024];
    int t = threadIdx.x;
    int i = blockIdx.x * 1024 + t;
    int v = (i < N) ? cnt[i] : 0;
    if (i < N) dis[i] = 1.0f / sqrtf((float)(v + 1));   // self-loop included
    tmp[t] = v;
    __syncthreads();
    for (int d = 1; d < 1024; d <<= 1) {
        int x = (t >= d) ? tmp[t - d] : 0;
        __syncthreads();
        tmp[t] += x;
        __syncthreads();
    }
    if (i < N) out[i] = tmp[t] - v;
    if (t == 1023) bsums[blockIdx.x] = tmp[t];
}

__global__ void k_scan2(int* __restrict__ bsums, int nb) {
    __shared__ int tmp[64];
    int t = threadIdx.x;
    int v = (t < nb) ? bsums[t] : 0;
    tmp[t] = v;
    __syncthreads();
    for (int d = 1; d < 64; d <<= 1) {
        int x = (t >= d) ? tmp[t - d] : 0;
        __syncthreads();
        tmp[t] += x;
        __syncthreads();
    }
    if (t < nb) bsums[t] = tmp[t] - v;
}

__global__ __launch_bounds__(1024) void k_scan3(int* __restrict__ off,
                                                const int* __restrict__ bsums,
                                                int N, int E) {
    int i = blockIdx.x * 1024 + threadIdx.x;
    if (i < N) off[i] += bsums[blockIdx.x];
    if (i == 0) off[N] = E;
}

// ---------------- fused: layer-1 MFMA GEMM (fp32 A) + distributed CSR fill --
// Every block is a GEMM block; each THREAD additionally owns up to 8 edges:
// prologue resolves pos = off[dst]+rank (overlaps GEMM staging), epilogue
// fires the scattered 2B stores (fire-and-forget, hidden by other blocks).
#define LDK 40
#define FILL_PER 8
__global__ __launch_bounds__(128) void k_mm1fill(
        const float* __restrict__ Af,
        const bf16_t* __restrict__ Wh, const bf16_t* __restrict__ Wl,
        const float* __restrict__ dis, bf16_t* __restrict__ Cb,
        int N, int K,
        const int* __restrict__ src, const int* __restrict__ dst,
        const int* __restrict__ off, const u16* __restrict__ rank,
        u16* __restrict__ csr16, int E, int totThreads) {
    __shared__ bf16_t AsH[64][LDK];
    __shared__ bf16_t AsL[64][LDK];
    __shared__ bf16_t BsH[128][LDK];
    __shared__ bf16_t BsL[128][LDK];

    const int t    = threadIdx.x;
    const int lane = t & 63;
    const int wave = t >> 6;            // 0,1
    const int row0 = blockIdx.x * 64;
    const int wn   = wave * 64;
    const int fm   = lane & 15;
    const int fq   = lane >> 4;

    // ---- fill prologue: resolve scatter addresses (dependent gathers now) --
    const int g = blockIdx.x * 128 + t;
    int epos[FILL_PER];
    u16 esrc[FILL_PER];
#pragma unroll
    for (int i = 0; i < FILL_PER; i++) {
        int e = g + i * totThreads;
        if (e < E) {
            int d = dst[e];
            epos[i] = off[d] + (int)rank[e];
            esrc[i] = (u16)src[e];
        } else {
            epos[i] = -1;
            esrc[i] = 0;
        }
    }

    f32x4 acc[4][4] = {};

    for (int k0 = 0; k0 < K; k0 += 32) {
        __syncthreads();
        // stage A: 64 rows x 32 k fp32 = 512 float4; split hi/lo
#pragma unroll
        for (int i = 0; i < 4; i++) {
            int idx = t + i * 128;
            int r   = idx >> 3;
            int c4  = idx & 7;
            int gr  = row0 + r;
            float4 v = make_float4(0.f, 0.f, 0.f, 0.f);
            if (gr < N) v = *(const float4*)(Af + (size_t)gr * K + k0 + c4 * 4);
            bf16_t h0 = (bf16_t)v.x, h1 = (bf16_t)v.y, h2 = (bf16_t)v.z, h3 = (bf16_t)v.w;
            bf16_t l0 = (bf16_t)(v.x - (float)h0);
            bf16_t l1 = (bf16_t)(v.y - (float)h1);
            bf16_t l2 = (bf16_t)(v.z - (float)h2);
            bf16_t l3 = (bf16_t)(v.w - (float)h3);
            *(bf16x4*)&AsH[r][c4 * 4] = (bf16x4){h0, h1, h2, h3};
            *(bf16x4*)&AsL[r][c4 * 4] = (bf16x4){l0, l1, l2, l3};
        }
        // stage B: 128 n x 32 k
#pragma unroll
        for (int i = 0; i < 4; i++) {
            int idx = t + i * 128;
            int r   = idx >> 2;
            int c8  = idx & 3;
            *(bf16x8*)&BsH[r][c8 * 8] = *(const bf16x8*)(Wh + (size_t)r * K + k0 + c8 * 8);
            *(bf16x8*)&BsL[r][c8 * 8] = *(const bf16x8*)(Wl + (size_t)r * K + k0 + c8 * 8);
        }
        __syncthreads();

        bf16x8 ah[4], al[4], bh[4], bl[4];
#pragma unroll
        for (int i = 0; i < 4; i++) {
            ah[i] = *(const bf16x8*)&AsH[i * 16 + fm][fq * 8];
            al[i] = *(const bf16x8*)&AsL[i * 16 + fm][fq * 8];
            bh[i] = *(const bf16x8*)&BsH[wn + i * 16 + fm][fq * 8];
            bl[i] = *(const bf16x8*)&BsL[wn + i * 16 + fm][fq * 8];
        }
#pragma unroll
        for (int mi = 0; mi < 4; mi++)
#pragma unroll
            for (int ni = 0; ni < 4; ni++) {
                acc[mi][ni] = __builtin_amdgcn_mfma_f32_16x16x32_bf16(ah[mi], bh[ni], acc[mi][ni], 0, 0, 0);
                acc[mi][ni] = __builtin_amdgcn_mfma_f32_16x16x32_bf16(ah[mi], bl[ni], acc[mi][ni], 0, 0, 0);
                acc[mi][ni] = __builtin_amdgcn_mfma_f32_16x16x32_bf16(al[mi], bh[ni], acc[mi][ni], 0, 0, 0);
            }
    }

#pragma unroll
    for (int mi = 0; mi < 4; mi++)
#pragma unroll
        for (int r = 0; r < 4; r++) {
            int grow = row0 + mi * 16 + fq * 4 + r;
            if (grow < N) {
                float dr = dis[grow];
#pragma unroll
                for (int ni = 0; ni < 4; ni++)
                    Cb[(size_t)grow * D_H + wn + ni * 16 + fm] = (bf16_t)(dr * acc[mi][ni][r]);
            }
        }

    // ---- fill epilogue: scattered 2B stores, fire and forget ----
#pragma unroll
    for (int i = 0; i < FILL_PER; i++)
        if (epos[i] >= 0) csr16[epos[i]] = esrc[i];
}

// ---------------- layer-2 MFMA GEMM (bf16 hi/lo A) ----------------
__global__ __launch_bounds__(128) void k_mm2(const bf16_t* __restrict__ Ah,
                                             const bf16_t* __restrict__ Al,
                                             const bf16_t* __restrict__ Wh,
                                             const bf16_t* __restrict__ Wl,
                                             const float* __restrict__ dis,
                                             bf16_t* __restrict__ Cb,
                                             int N, int K) {
    __shared__ bf16_t AsH[64][LDK];
    __shared__ bf16_t AsL[64][LDK];
    __shared__ bf16_t BsH[128][LDK];
    __shared__ bf16_t BsL[128][LDK];

    const int t    = threadIdx.x;
    const int lane = t & 63;
    const int wave = t >> 6;
    const int row0 = blockIdx.x * 64;
    const int wn   = wave * 64;
    const int fm   = lane & 15;
    const int fq   = lane >> 4;

    f32x4 acc[4][4] = {};

    for (int k0 = 0; k0 < K; k0 += 32) {
        __syncthreads();
#pragma unroll
        for (int i = 0; i < 2; i++) {
            int idx = t + i * 128;
            int r   = idx >> 2;
            int c8  = idx & 3;
            int gr  = row0 + r;
            bf16x8 vh = {}, vl = {};
            if (gr < N) {
                vh = *(const bf16x8*)(Ah + (size_t)gr * K + k0 + c8 * 8);
                vl = *(const bf16x8*)(Al + (size_t)gr * K + k0 + c8 * 8);
            }
            *(bf16x8*)&AsH[r][c8 * 8] = vh;
            *(bf16x8*)&AsL[r][c8 * 8] = vl;
        }
#pragma unroll
        for (int i = 0; i < 4; i++) {
            int idx = t + i * 128;
            int r   = idx >> 2;
            int c8  = idx & 3;
            *(bf16x8*)&BsH[r][c8 * 8] = *(const bf16x8*)(Wh + (size_t)r * K + k0 + c8 * 8);
            *(bf16x8*)&BsL[r][c8 * 8] = *(const bf16x8*)(Wl + (size_t)r * K + k0 + c8 * 8);
        }
        __syncthreads();

        bf16x8 ah[4], al[4], bh[4], bl[4];
#pragma unroll
        for (int i = 0; i < 4; i++) {
            ah[i] = *(const bf16x8*)&AsH[i * 16 + fm][fq * 8];
            al[i] = *(const bf16x8*)&AsL[i * 16 + fm][fq * 8];
            bh[i] = *(const bf16x8*)&BsH[wn + i * 16 + fm][fq * 8];
            bl[i] = *(const bf16x8*)&BsL[wn + i * 16 + fm][fq * 8];
        }
#pragma unroll
        for (int mi = 0; mi < 4; mi++)
#pragma unroll
            for (int ni = 0; ni < 4; ni++) {
                acc[mi][ni] = __builtin_amdgcn_mfma_f32_16x16x32_bf16(ah[mi], bh[ni], acc[mi][ni], 0, 0, 0);
                acc[mi][ni] = __builtin_amdgcn_mfma_f32_16x16x32_bf16(ah[mi], bl[ni], acc[mi][ni], 0, 0, 0);
                acc[mi][ni] = __builtin_amdgcn_mfma_f32_16x16x32_bf16(al[mi], bh[ni], acc[mi][ni], 0, 0, 0);
            }
    }

#pragma unroll
    for (int mi = 0; mi < 4; mi++)
#pragma unroll
        for (int r = 0; r < 4; r++) {
            int grow = row0 + mi * 16 + fq * 4 + r;
            if (grow < N) {
                float dr = dis[grow];
#pragma unroll
                for (int ni = 0; ni < 4; ni++)
                    Cb[(size_t)grow * D_H + wn + ni * 16 + fm] = (bf16_t)(dr * acc[mi][ni][r]);
            }
        }
}

// ---------------- aggregation ----------------
// Input Hb = bf16 dis-scaled rows H'. out[i] = (relu?)(b + di*(H'[i] + sum_s H'[s]))
// 32 lanes per node (bf16x4/lane = 8B, row = 256B), 8 nodes per 256-block.
__global__ __launch_bounds__(256) void k_agg(const bf16_t* __restrict__ Hb,
                                             const float* __restrict__ dis,
                                             const int* __restrict__ off,
                                             const u16* __restrict__ csr16,
                                             const float4* __restrict__ bias4,
                                             float4* __restrict__ outF,
                                             bf16_t* __restrict__ outH,
                                             bf16_t* __restrict__ outL,
                                             int N, int mode) {
    const int half = threadIdx.x >> 5;
    const int lane = threadIdx.x & 31;
    const int node = blockIdx.x * 8 + half;
    if (node >= N) return;

    const size_t loff = (size_t)lane * 4;

    bf16x4 vs = *(const bf16x4*)(Hb + (size_t)node * D_H + loff);
    float4 a0 = make_float4((float)vs[0], (float)vs[1], (float)vs[2], (float)vs[3]);
    float4 a1 = {0,0,0,0}, a2 = {0,0,0,0}, a3 = {0,0,0,0};
    float4 a4 = {0,0,0,0}, a5 = {0,0,0,0}, a6 = {0,0,0,0}, a7 = {0,0,0,0};

    int p  = off[node];
    int p1 = off[node + 1];

    for (; p + 8 <= p1; p += 8) {
        int s0 = (int)csr16[p + 0], s1 = (int)csr16[p + 1];
        int s2 = (int)csr16[p + 2], s3 = (int)csr16[p + 3];
        int s4 = (int)csr16[p + 4], s5 = (int)csr16[p + 5];
        int s6 = (int)csr16[p + 6], s7 = (int)csr16[p + 7];
        bf16x4 h0 = *(const bf16x4*)(Hb + (size_t)s0 * D_H + loff);
        bf16x4 h1 = *(const bf16x4*)(Hb + (size_t)s1 * D_H + loff);
        bf16x4 h2 = *(const bf16x4*)(Hb + (size_t)s2 * D_H + loff);
        bf16x4 h3 = *(const bf16x4*)(Hb + (size_t)s3 * D_H + loff);
        bf16x4 h4 = *(const bf16x4*)(Hb + (size_t)s4 * D_H + loff);
        bf16x4 h5 = *(const bf16x4*)(Hb + (size_t)s5 * D_H + loff);
        bf16x4 h6 = *(const bf16x4*)(Hb + (size_t)s6 * D_H + loff);
        bf16x4 h7 = *(const bf16x4*)(Hb + (size_t)s7 * D_H + loff);
        a0.x += (float)h0[0]; a0.y += (float)h0[1]; a0.z += (float)h0[2]; a0.w += (float)h0[3];
        a1.x += (float)h1[0]; a1.y += (float)h1[1]; a1.z += (float)h1[2]; a1.w += (float)h1[3];
        a2.x += (float)h2[0]; a2.y += (float)h2[1]; a2.z += (float)h2[2]; a2.w += (float)h2[3];
        a3.x += (float)h3[0]; a3.y += (float)h3[1]; a3.z += (float)h3[2]; a3.w += (float)h3[3];
        a4.x += (float)h4[0]; a4.y += (float)h4[1]; a4.z += (float)h4[2]; a4.w += (float)h4[3];
        a5.x += (float)h5[0]; a5.y += (float)h5[1]; a5.z += (float)h5[2]; a5.w += (float)h5[3];
        a6.x += (float)h6[0]; a6.y += (float)h6[1]; a6.z += (float)h6[2]; a6.w += (float)h6[3];
        a7.x += (float)h7[0]; a7.y += (float)h7[1]; a7.z += (float)h7[2]; a7.w += (float)h7[3];
    }
    if (p + 4 <= p1) {
        int s0 = (int)csr16[p + 0], s1 = (int)csr16[p + 1];
        int s2 = (int)csr16[p + 2], s3 = (int)csr16[p + 3];
        bf16x4 h0 = *(const bf16x4*)(Hb + (size_t)s0 * D_H + loff);
        bf16x4 h1 = *(const bf16x4*)(Hb + (size_t)s1 * D_H + loff);
        bf16x4 h2 = *(const bf16x4*)(Hb + (size_t)s2 * D_H + loff);
        bf16x4 h3 = *(const bf16x4*)(Hb + (size_t)s3 * D_H + loff);
        a0.x += (float)h0[0]; a0.y += (float)h0[1]; a0.z += (float)h0[2]; a0.w += (float)h0[3];
        a1.x += (float)h1[0]; a1.y += (float)h1[1]; a1.z += (float)h1[2]; a1.w += (float)h1[3];
        a2.x += (float)h2[0]; a2.y += (float)h2[1]; a2.z += (float)h2[2]; a2.w += (float)h2[3];
        a3.x += (float)h3[0]; a3.y += (float)h3[1]; a3.z += (float)h3[2]; a3.w += (float)h3[3];
        p += 4;
    }
    for (; p < p1; p++) {
        int s0 = (int)csr16[p];
        bf16x4 h0 = *(const bf16x4*)(Hb + (size_t)s0 * D_H + loff);
        a0.x += (float)h0[0]; a0.y += (float)h0[1]; a0.z += (float)h0[2]; a0.w += (float)h0[3];
    }

    float4 sum;
    sum.x = ((a0.x + a1.x) + (a2.x + a3.x)) + ((a4.x + a5.x) + (a6.x + a7.x));
    sum.y = ((a0.y + a1.y) + (a2.y + a3.y)) + ((a4.y + a5.y) + (a6.y + a7.y));
    sum.z = ((a0.z + a1.z) + (a2.z + a3.z)) + ((a4.z + a5.z) + (a6.z + a7.z));
    sum.w = ((a0.w + a1.w) + (a2.w + a3.w)) + ((a4.w + a5.w) + (a6.w + a7.w));

    const float  di = dis[node];
    const float4 bv = bias4[lane];
    float vx = fmaf(di, sum.x, bv.x);
    float vy = fmaf(di, sum.y, bv.y);
    float vz = fmaf(di, sum.z, bv.z);
    float vw = fmaf(di, sum.w, bv.w);

    if (mode == 1) {
        vx = fmaxf(vx, 0.0f); vy = fmaxf(vy, 0.0f);
        vz = fmaxf(vz, 0.0f); vw = fmaxf(vw, 0.0f);
        bf16_t hx = (bf16_t)vx, hy = (bf16_t)vy, hz = (bf16_t)vz, hw = (bf16_t)vw;
        bf16_t lx = (bf16_t)(vx - (float)hx);
        bf16_t ly = (bf16_t)(vy - (float)hy);
        bf16_t lz = (bf16_t)(vz - (float)hz);
        bf16_t lw = (bf16_t)(vw - (float)hw);
        *(bf16x4*)(outH + (size_t)node * D_H + loff) = (bf16x4){hx, hy, hz, hw};
        *(bf16x4*)(outL + (size_t)node * D_H + loff) = (bf16x4){lx, ly, lz, lw};
    } else {
        outF[(size_t)node * 32 + lane] = make_float4(vx, vy, vz, vw);
    }
}

extern "C" void kernel_launch(void* const* d_in, const int* in_sizes, int n_in,
                              void* d_out, int out_size, void* d_ws, size_t ws_size,
                              hipStream_t stream) {
    const float* X  = (const float*)d_in[0];
    const int*   ei = (const int*)d_in[1];
    const float* W1 = (const float*)d_in[2];
    const float* b1 = (const float*)d_in[3];
    const float* W2 = (const float*)d_in[4];
    const float* b2 = (const float*)d_in[5];
    float* out = (float*)d_out;

    const int N  = in_sizes[0] / 256;   // 50000
    const int E  = in_sizes[1] / 2;     // 800000
    const int K1 = 256;

    const int* src = ei;
    const int* dst = ei + E;

    uintptr_t p = (uintptr_t)d_ws;
    auto carve = [&](size_t bytes) {
        uintptr_t q = p;
        p += (bytes + 255) & ~(size_t)255;
        return q;
    };
    int*    cnt   = (int*)carve((size_t)N * 4);
    int*    off   = (int*)carve((size_t)(N + 1) * 4);
    int*    bsums = (int*)carve(64 * 4);
    float*  dis   = (float*)carve((size_t)N * 4);
    u16*    rank  = (u16*)carve((size_t)E * 2);
    u16*    csr16 = (u16*)carve((size_t)E * 2);
    bf16_t* Hb    = (bf16_t*)carve((size_t)N * D_H * 2);
    bf16_t* X1h   = (bf16_t*)carve((size_t)N * D_H * 2);
    bf16_t* X1l   = (bf16_t*)carve((size_t)N * D_H * 2);
    bf16_t* W1h   = (bf16_t*)carve((size_t)K1 * D_H * 2);
    bf16_t* W1l   = (bf16_t*)carve((size_t)K1 * D_H * 2);
    bf16_t* W2h   = (bf16_t*)carve((size_t)D_H * D_H * 2);
    bf16_t* W2l   = (bf16_t*)carve((size_t)D_H * D_H * 2);

    const int nb = (N + 1023) / 1024;

    // graph preprocessing (+ weight prep fused into countrank's grid)
    hipMemsetAsync(cnt, 0, (size_t)N * 4, stream);
    const int gcr   = (E + 255) / 256;
    const int gprep = (K1 * 128 + D_H * 128 + 255) / 256;
    k_countrank<<<gcr + gprep, 256, 0, stream>>>(dst, cnt, rank, E, gcr,
                                                 W1, W1h, W1l, K1,
                                                 W2, W2h, W2l, D_H);
    k_scan1<<<nb, 1024, 0, stream>>>(cnt, off, bsums, dis, N);
    k_scan2<<<1, 64, 0, stream>>>(bsums, nb);
    k_scan3<<<nb, 1024, 0, stream>>>(off, bsums, N, E);

    const int gmm = (N + 63) / 64;          // 782 GEMM blocks
    const int gag = (N + 7) / 8;

    // layer 1 GEMM with distributed CSR fill
    k_mm1fill<<<gmm, 128, 0, stream>>>(X, W1h, W1l, dis, Hb, N, K1,
                                       src, dst, off, rank, csr16, E, gmm * 128);
    k_agg<<<gag, 256, 0, stream>>>(Hb, dis, off, csr16,
                                   (const float4*)b1, nullptr, X1h, X1l, N, 1);

    // layer 2
    k_mm2<<<gmm, 128, 0, stream>>>(X1h, X1l, W2h, W2l, dis, Hb, N, D_H);
    k_agg<<<gag, 256, 0, stream>>>(Hb, dis, off, csr16,
                                   (const float4*)b2, (float4*)out, nullptr, nullptr, N, 0);
}

// Round 8
// 251.400 us; speedup vs baseline: 2.2343x; 1.0555x over previous
//
#include <hip/hip_runtime.h>
#include <hip/hip_bf16.h>
#include <stdint.h>

#define D_H 128

typedef __bf16 bf16_t;
typedef unsigned short u16;
typedef bf16_t bf16x8 __attribute__((ext_vector_type(8)));
typedef bf16_t bf16x4 __attribute__((ext_vector_type(4)));
typedef float  f32x4  __attribute__((ext_vector_type(4)));

// ---------------- degree count + rank capture + weight prep (fused) --------
__global__ void k_countrank(const int* __restrict__ dst, int* __restrict__ cnt,
                            u16* __restrict__ rank, int E, int crBlocks,
                            const float* __restrict__ W1, bf16_t* __restrict__ W1h,
                            bf16_t* __restrict__ W1l, int K1,
                            const float* __restrict__ W2, bf16_t* __restrict__ W2h,
                            bf16_t* __restrict__ W2l, int K2) {
    if ((int)blockIdx.x < crBlocks) {
        int e = blockIdx.x * 256 + threadIdx.x;
        if (e < E) rank[e] = (u16)atomicAdd(&cnt[dst[e]], 1);
        return;
    }
    int id = ((int)blockIdx.x - crBlocks) * 256 + threadIdx.x;
    int n1 = K1 * 128;
    if (id < n1) {
        int k = id >> 7, n = id & 127;
        float w = W1[id];
        bf16_t h = (bf16_t)w;
        W1h[(size_t)n * K1 + k] = h;
        W1l[(size_t)n * K1 + k] = (bf16_t)(w - (float)h);
    } else if (id < n1 + K2 * 128) {
        int id2 = id - n1;
        int k = id2 >> 7, n = id2 & 127;
        float w = W2[id2];
        bf16_t h = (bf16_t)w;
        W2h[(size_t)n * K2 + k] = h;
        W2l[(size_t)n * K2 + k] = (bf16_t)(w - (float)h);
    }
}

// ---------------- exclusive scan (3 kernels); scan1 also emits dis ----------
__global__ __launch_bounds__(1024) void k_scan1(const int* __restrict__ cnt,
                                                int* __restrict__ out,
                                                int* __restrict__ bsums,
                                                float* __restrict__ dis, int N) {
    __shared__ int tmp[1024];
    int t = threadIdx.x;
    int i = blockIdx.x * 1024 + t;
    int v = (i < N) ? cnt[i] : 0;
    if (i < N) dis[i] = 1.0f / sqrtf((float)(v + 1));
    tmp[t] = v;
    __syncthreads();
    for (int d = 1; d < 1024; d <<= 1) {
        int x = (t >= d) ? tmp[t - d] : 0;
        __syncthreads();
        tmp[t] += x;
        __syncthreads();
    }
    if (i < N) out[i] = tmp[t] - v;
    if (t == 1023) bsums[blockIdx.x] = tmp[t];
}

__global__ void k_scan2(int* __restrict__ bsums, int nb) {
    __shared__ int tmp[64];
    int t = threadIdx.x;
    int v = (t < nb) ? bsums[t] : 0;
    tmp[t] = v;
    __syncthreads();
    for (int d = 1; d < 64; d <<= 1) {
        int x = (t >= d) ? tmp[t - d] : 0;
        __syncthreads();
        tmp[t] += x;
        __syncthreads();
    }
    if (t < nb) bsums[t] = tmp[t] - v;
}

__global__ __launch_bounds__(1024) void k_scan3(int* __restrict__ off,
                                                const int* __restrict__ bsums,
                                                int N, int E) {
    int i = blockIdx.x * 1024 + threadIdx.x;
    if (i < N) off[i] += bsums[blockIdx.x];
    if (i == 0) off[N] = E;
}

// ---------------- MFMA GEMM tiles: BM=64, BN=64, 256 thr = 4 waves --------
// Each wave computes 32x32 (2x2 tiles of 16x16x32). Grid = (N/64)*2 blocks
// = 1564 -> ~6 blocks/CU, ~24 waves/CU: latency hidden by co-residency.
// blockIdx decode: row0 = (bx>>1)*64, col0 = (bx&1)*64.
#define LDK 40
#define FILL_PER 2

// layer-1 (fp32 A, hi/lo split in-kernel) + distributed CSR fill
__global__ __launch_bounds__(256) void k_mm1fill(
        const float* __restrict__ Af,
        const bf16_t* __restrict__ Wh, const bf16_t* __restrict__ Wl,
        const float* __restrict__ dis, bf16_t* __restrict__ Cb,
        int N, int K,
        const int* __restrict__ src, const int* __restrict__ dst,
        const int* __restrict__ off, const u16* __restrict__ rank,
        u16* __restrict__ csr16, int E, int totThreads) {
    __shared__ bf16_t AsH[64][LDK];
    __shared__ bf16_t AsL[64][LDK];
    __shared__ bf16_t BsH[64][LDK];
    __shared__ bf16_t BsL[64][LDK];

    const int t    = threadIdx.x;
    const int lane = t & 63;
    const int wave = t >> 6;            // 0..3
    const int row0 = ((int)blockIdx.x >> 1) * 64;
    const int col0 = ((int)blockIdx.x & 1) * 64;
    const int wm   = (wave & 1) * 32;
    const int wn   = (wave >> 1) * 32;
    const int fm   = lane & 15;
    const int fq   = lane >> 4;

    // ---- fill prologue: resolve scatter addresses ----
    const int g = (int)blockIdx.x * 256 + t;
    int epos[FILL_PER];
    u16 esrc[FILL_PER];
#pragma unroll
    for (int i = 0; i < FILL_PER; i++) {
        int e = g + i * totThreads;
        if (e < E) {
            int d = dst[e];
            epos[i] = off[d] + (int)rank[e];
            esrc[i] = (u16)src[e];
        } else {
            epos[i] = -1;
            esrc[i] = 0;
        }
    }

    f32x4 acc[2][2] = {};

    for (int k0 = 0; k0 < K; k0 += 32) {
        __syncthreads();
        // stage A: 64 rows x 32 k fp32 = 512 float4; 2/thread, split hi/lo
#pragma unroll
        for (int i = 0; i < 2; i++) {
            int idx = t + i * 256;
            int r   = idx >> 3;
            int c4  = idx & 7;
            int gr  = row0 + r;
            float4 v = make_float4(0.f, 0.f, 0.f, 0.f);
            if (gr < N) v = *(const float4*)(Af + (size_t)gr * K + k0 + c4 * 4);
            bf16_t h0 = (bf16_t)v.x, h1 = (bf16_t)v.y, h2 = (bf16_t)v.z, h3 = (bf16_t)v.w;
            bf16_t l0 = (bf16_t)(v.x - (float)h0);
            bf16_t l1 = (bf16_t)(v.y - (float)h1);
            bf16_t l2 = (bf16_t)(v.z - (float)h2);
            bf16_t l3 = (bf16_t)(v.w - (float)h3);
            *(bf16x4*)&AsH[r][c4 * 4] = (bf16x4){h0, h1, h2, h3};
            *(bf16x4*)&AsL[r][c4 * 4] = (bf16x4){l0, l1, l2, l3};
        }
        // stage B: 64 cols x 32 k, 256 bf16x8 per plane; 1/thread per plane
        {
            int r  = t >> 2;
            int c8 = t & 3;
            *(bf16x8*)&BsH[r][c8 * 8] = *(const bf16x8*)(Wh + (size_t)(col0 + r) * K + k0 + c8 * 8);
            *(bf16x8*)&BsL[r][c8 * 8] = *(const bf16x8*)(Wl + (size_t)(col0 + r) * K + k0 + c8 * 8);
        }
        __syncthreads();

        bf16x8 ah[2], al[2], bh[2], bl[2];
#pragma unroll
        for (int i = 0; i < 2; i++) {
            ah[i] = *(const bf16x8*)&AsH[wm + i * 16 + fm][fq * 8];
            al[i] = *(const bf16x8*)&AsL[wm + i * 16 + fm][fq * 8];
            bh[i] = *(const bf16x8*)&BsH[wn + i * 16 + fm][fq * 8];
            bl[i] = *(const bf16x8*)&BsL[wn + i * 16 + fm][fq * 8];
        }
#pragma unroll
        for (int mi = 0; mi < 2; mi++)
#pragma unroll
            for (int ni = 0; ni < 2; ni++) {
                acc[mi][ni] = __builtin_amdgcn_mfma_f32_16x16x32_bf16(ah[mi], bh[ni], acc[mi][ni], 0, 0, 0);
                acc[mi][ni] = __builtin_amdgcn_mfma_f32_16x16x32_bf16(ah[mi], bl[ni], acc[mi][ni], 0, 0, 0);
                acc[mi][ni] = __builtin_amdgcn_mfma_f32_16x16x32_bf16(al[mi], bh[ni], acc[mi][ni], 0, 0, 0);
            }
    }

#pragma unroll
    for (int mi = 0; mi < 2; mi++)
#pragma unroll
        for (int r = 0; r < 4; r++) {
            int grow = row0 + wm + mi * 16 + fq * 4 + r;
            if (grow < N) {
                float dr = dis[grow];
#pragma unroll
                for (int ni = 0; ni < 2; ni++)
                    Cb[(size_t)grow * D_H + col0 + wn + ni * 16 + fm] = (bf16_t)(dr * acc[mi][ni][r]);
            }
        }

    // ---- fill epilogue: scattered 2B stores, fire and forget ----
#pragma unroll
    for (int i = 0; i < FILL_PER; i++)
        if (epos[i] >= 0) csr16[epos[i]] = esrc[i];
}

// layer-2 (bf16 hi/lo A)
__global__ __launch_bounds__(256) void k_mm2(const bf16_t* __restrict__ Ah,
                                             const bf16_t* __restrict__ Al,
                                             const bf16_t* __restrict__ Wh,
                                             const bf16_t* __restrict__ Wl,
                                             const float* __restrict__ dis,
                                             bf16_t* __restrict__ Cb,
                                             int N, int K) {
    __shared__ bf16_t AsH[64][LDK];
    __shared__ bf16_t AsL[64][LDK];
    __shared__ bf16_t BsH[64][LDK];
    __shared__ bf16_t BsL[64][LDK];

    const int t    = threadIdx.x;
    const int lane = t & 63;
    const int wave = t >> 6;
    const int row0 = ((int)blockIdx.x >> 1) * 64;
    const int col0 = ((int)blockIdx.x & 1) * 64;
    const int wm   = (wave & 1) * 32;
    const int wn   = (wave >> 1) * 32;
    const int fm   = lane & 15;
    const int fq   = lane >> 4;

    f32x4 acc[2][2] = {};

    for (int k0 = 0; k0 < K; k0 += 32) {
        __syncthreads();
        // stage A: 64 rows x 32 k, 256 bf16x8 per plane; 1/thread per plane
        {
            int r  = t >> 2;
            int c8 = t & 3;
            int gr = row0 + r;
            bf16x8 vh = {}, vl = {};
            if (gr < N) {
                vh = *(const bf16x8*)(Ah + (size_t)gr * K + k0 + c8 * 8);
                vl = *(const bf16x8*)(Al + (size_t)gr * K + k0 + c8 * 8);
            }
            *(bf16x8*)&AsH[r][c8 * 8] = vh;
            *(bf16x8*)&AsL[r][c8 * 8] = vl;
        }
        // stage B
        {
            int r  = t >> 2;
            int c8 = t & 3;
            *(bf16x8*)&BsH[r][c8 * 8] = *(const bf16x8*)(Wh + (size_t)(col0 + r) * K + k0 + c8 * 8);
            *(bf16x8*)&BsL[r][c8 * 8] = *(const bf16x8*)(Wl + (size_t)(col0 + r) * K + k0 + c8 * 8);
        }
        __syncthreads();

        bf16x8 ah[2], al[2], bh[2], bl[2];
#pragma unroll
        for (int i = 0; i < 2; i++) {
            ah[i] = *(const bf16x8*)&AsH[wm + i * 16 + fm][fq * 8];
            al[i] = *(const bf16x8*)&AsL[wm + i * 16 + fm][fq * 8];
            bh[i] = *(const bf16x8*)&BsH[wn + i * 16 + fm][fq * 8];
            bl[i] = *(const bf16x8*)&BsL[wn + i * 16 + fm][fq * 8];
        }
#pragma unroll
        for (int mi = 0; mi < 2; mi++)
#pragma unroll
            for (int ni = 0; ni < 2; ni++) {
                acc[mi][ni] = __builtin_amdgcn_mfma_f32_16x16x32_bf16(ah[mi], bh[ni], acc[mi][ni], 0, 0, 0);
                acc[mi][ni] = __builtin_amdgcn_mfma_f32_16x16x32_bf16(ah[mi], bl[ni], acc[mi][ni], 0, 0, 0);
                acc[mi][ni] = __builtin_amdgcn_mfma_f32_16x16x32_bf16(al[mi], bh[ni], acc[mi][ni], 0, 0, 0);
            }
    }

#pragma unroll
    for (int mi = 0; mi < 2; mi++)
#pragma unroll
        for (int r = 0; r < 4; r++) {
            int grow = row0 + wm + mi * 16 + fq * 4 + r;
            if (grow < N) {
                float dr = dis[grow];
#pragma unroll
                for (int ni = 0; ni < 2; ni++)
                    Cb[(size_t)grow * D_H + col0 + wn + ni * 16 + fm] = (bf16_t)(dr * acc[mi][ni][r]);
            }
        }
}

// ---------------- aggregation ----------------
__global__ __launch_bounds__(256) void k_agg(const bf16_t* __restrict__ Hb,
                                             const float* __restrict__ dis,
                                             const int* __restrict__ off,
                                             const u16* __restrict__ csr16,
                                             const float4* __restrict__ bias4,
                                             float4* __restrict__ outF,
                                             bf16_t* __restrict__ outH,
                                             bf16_t* __restrict__ outL,
                                             int N, int mode) {
    const int half = threadIdx.x >> 5;
    const int lane = threadIdx.x & 31;
    const int node = blockIdx.x * 8 + half;
    if (node >= N) return;

    const size_t loff = (size_t)lane * 4;

    bf16x4 vs = *(const bf16x4*)(Hb + (size_t)node * D_H + loff);
    float4 a0 = make_float4((float)vs[0], (float)vs[1], (float)vs[2], (float)vs[3]);
    float4 a1 = {0,0,0,0}, a2 = {0,0,0,0}, a3 = {0,0,0,0};
    float4 a4 = {0,0,0,0}, a5 = {0,0,0,0}, a6 = {0,0,0,0}, a7 = {0,0,0,0};

    int p  = off[node];
    int p1 = off[node + 1];

    for (; p + 8 <= p1; p += 8) {
        int s0 = (int)csr16[p + 0], s1 = (int)csr16[p + 1];
        int s2 = (int)csr16[p + 2], s3 = (int)csr16[p + 3];
        int s4 = (int)csr16[p + 4], s5 = (int)csr16[p + 5];
        int s6 = (int)csr16[p + 6], s7 = (int)csr16[p + 7];
        bf16x4 h0 = *(const bf16x4*)(Hb + (size_t)s0 * D_H + loff);
        bf16x4 h1 = *(const bf16x4*)(Hb + (size_t)s1 * D_H + loff);
        bf16x4 h2 = *(const bf16x4*)(Hb + (size_t)s2 * D_H + loff);
        bf16x4 h3 = *(const bf16x4*)(Hb + (size_t)s3 * D_H + loff);
        bf16x4 h4 = *(const bf16x4*)(Hb + (size_t)s4 * D_H + loff);
        bf16x4 h5 = *(const bf16x4*)(Hb + (size_t)s5 * D_H + loff);
        bf16x4 h6 = *(const bf16x4*)(Hb + (size_t)s6 * D_H + loff);
        bf16x4 h7 = *(const bf16x4*)(Hb + (size_t)s7 * D_H + loff);
        a0.x += (float)h0[0]; a0.y += (float)h0[1]; a0.z += (float)h0[2]; a0.w += (float)h0[3];
        a1.x += (float)h1[0]; a1.y += (float)h1[1]; a1.z += (float)h1[2]; a1.w += (float)h1[3];
        a2.x += (float)h2[0]; a2.y += (float)h2[1]; a2.z += (float)h2[2]; a2.w += (float)h2[3];
        a3.x += (float)h3[0]; a3.y += (float)h3[1]; a3.z += (float)h3[2]; a3.w += (float)h3[3];
        a4.x += (float)h4[0]; a4.y += (float)h4[1]; a4.z += (float)h4[2]; a4.w += (float)h4[3];
        a5.x += (float)h5[0]; a5.y += (float)h5[1]; a5.z += (float)h5[2]; a5.w += (float)h5[3];
        a6.x += (float)h6[0]; a6.y += (float)h6[1]; a6.z += (float)h6[2]; a6.w += (float)h6[3];
        a7.x += (float)h7[0]; a7.y += (float)h7[1]; a7.z += (float)h7[2]; a7.w += (float)h7[3];
    }
    if (p + 4 <= p1) {
        int s0 = (int)csr16[p + 0], s1 = (int)csr16[p + 1];
        int s2 = (int)csr16[p + 2], s3 = (int)csr16[p + 3];
        bf16x4 h0 = *(const bf16x4*)(Hb + (size_t)s0 * D_H + loff);
        bf16x4 h1 = *(const bf16x4*)(Hb + (size_t)s1 * D_H + loff);
        bf16x4 h2 = *(const bf16x4*)(Hb + (size_t)s2 * D_H + loff);
        bf16x4 h3 = *(const bf16x4*)(Hb + (size_t)s3 * D_H + loff);
        a0.x += (float)h0[0]; a0.y += (float)h0[1]; a0.z += (float)h0[2]; a0.w += (float)h0[3];
        a1.x += (float)h1[0]; a1.y += (float)h1[1]; a1.z += (float)h1[2]; a1.w += (float)h1[3];
        a2.x += (float)h2[0]; a2.y += (float)h2[1]; a2.z += (float)h2[2]; a2.w += (float)h2[3];
        a3.x += (float)h3[0]; a3.y += (float)h3[1]; a3.z += (float)h3[2]; a3.w += (float)h3[3];
        p += 4;
    }
    for (; p < p1; p++) {
        int s0 = (int)csr16[p];
        bf16x4 h0 = *(const bf16x4*)(Hb + (size_t)s0 * D_H + loff);
        a0.x += (float)h0[0]; a0.y += (float)h0[1]; a0.z += (float)h0[2]; a0.w += (float)h0[3];
    }

    float4 sum;
    sum.x = ((a0.x + a1.x) + (a2.x + a3.x)) + ((a4.x + a5.x) + (a6.x + a7.x));
    sum.y = ((a0.y + a1.y) + (a2.y + a3.y)) + ((a4.y + a5.y) + (a6.y + a7.y));
    sum.z = ((a0.z + a1.z) + (a2.z + a3.z)) + ((a4.z + a5.z) + (a6.z + a7.z));
    sum.w = ((a0.w + a1.w) + (a2.w + a3.w)) + ((a4.w + a5.w) + (a6.w + a7.w));

    const float  di = dis[node];
    const float4 bv = bias4[lane];
    float vx = fmaf(di, sum.x, bv.x);
    float vy = fmaf(di, sum.y, bv.y);
    float vz = fmaf(di, sum.z, bv.z);
    float vw = fmaf(di, sum.w, bv.w);

    if (mode == 1) {
        vx = fmaxf(vx, 0.0f); vy = fmaxf(vy, 0.0f);
        vz = fmaxf(vz, 0.0f); vw = fmaxf(vw, 0.0f);
        bf16_t hx = (bf16_t)vx, hy = (bf16_t)vy, hz = (bf16_t)vz, hw = (bf16_t)vw;
        bf16_t lx = (bf16_t)(vx - (float)hx);
        bf16_t ly = (bf16_t)(vy - (float)hy);
        bf16_t lz = (bf16_t)(vz - (float)hz);
        bf16_t lw = (bf16_t)(vw - (float)hw);
        *(bf16x4*)(outH + (size_t)node * D_H + loff) = (bf16x4){hx, hy, hz, hw};
        *(bf16x4*)(outL + (size_t)node * D_H + loff) = (bf16x4){lx, ly, lz, lw};
    } else {
        outF[(size_t)node * 32 + lane] = make_float4(vx, vy, vz, vw);
    }
}

extern "C" void kernel_launch(void* const* d_in, const int* in_sizes, int n_in,
                              void* d_out, int out_size, void* d_ws, size_t ws_size,
                              hipStream_t stream) {
    const float* X  = (const float*)d_in[0];
    const int*   ei = (const int*)d_in[1];
    const float* W1 = (const float*)d_in[2];
    const float* b1 = (const float*)d_in[3];
    const float* W2 = (const float*)d_in[4];
    const float* b2 = (const float*)d_in[5];
    float* out = (float*)d_out;

    const int N  = in_sizes[0] / 256;   // 50000
    const int E  = in_sizes[1] / 2;     // 800000
    const int K1 = 256;

    const int* src = ei;
    const int* dst = ei + E;

    uintptr_t p = (uintptr_t)d_ws;
    auto carve = [&](size_t bytes) {
        uintptr_t q = p;
        p += (bytes + 255) & ~(size_t)255;
        return q;
    };
    int*    cnt   = (int*)carve((size_t)N * 4);
    int*    off   = (int*)carve((size_t)(N + 1) * 4);
    int*    bsums = (int*)carve(64 * 4);
    float*  dis   = (float*)carve((size_t)N * 4);
    u16*    rank  = (u16*)carve((size_t)E * 2);
    u16*    csr16 = (u16*)carve((size_t)E * 2);
    bf16_t* Hb    = (bf16_t*)carve((size_t)N * D_H * 2);
    bf16_t* X1h   = (bf16_t*)carve((size_t)N * D_H * 2);
    bf16_t* X1l   = (bf16_t*)carve((size_t)N * D_H * 2);
    bf16_t* W1h   = (bf16_t*)carve((size_t)K1 * D_H * 2);
    bf16_t* W1l   = (bf16_t*)carve((size_t)K1 * D_H * 2);
    bf16_t* W2h   = (bf16_t*)carve((size_t)D_H * D_H * 2);
    bf16_t* W2l   = (bf16_t*)carve((size_t)D_H * D_H * 2);

    const int nb = (N + 1023) / 1024;

    // graph preprocessing (+ weight prep fused into countrank's grid)
    hipMemsetAsync(cnt, 0, (size_t)N * 4, stream);
    const int gcr   = (E + 255) / 256;
    const int gprep = (K1 * 128 + D_H * 128 + 255) / 256;
    k_countrank<<<gcr + gprep, 256, 0, stream>>>(dst, cnt, rank, E, gcr,
                                                 W1, W1h, W1l, K1,
                                                 W2, W2h, W2l, D_H);
    k_scan1<<<nb, 1024, 0, stream>>>(cnt, off, bsums, dis, N);
    k_scan2<<<1, 64, 0, stream>>>(bsums, nb);
    k_scan3<<<nb, 1024, 0, stream>>>(off, bsums, N, E);

    const int gmm = ((N + 63) / 64) * 2;    // 1564 blocks (row x col split)
    const int gag = (N + 7) / 8;

    // layer 1 GEMM with distributed CSR fill
    k_mm1fill<<<gmm, 256, 0, stream>>>(X, W1h, W1l, dis, Hb, N, K1,
                                       src, dst, off, rank, csr16, E, gmm * 256);
    k_agg<<<gag, 256, 0, stream>>>(Hb, dis, off, csr16,
                                   (const float4*)b1, nullptr, X1h, X1l, N, 1);

    // layer 2
    k_mm2<<<gmm, 256, 0, stream>>>(X1h, X1l, W2h, W2l, dis, Hb, N, D_H);
    k_agg<<<gag, 256, 0, stream>>>(Hb, dis, off, csr16,
                                   (const float4*)b2, (float4*)out, nullptr, nullptr, N, 0);
}